// Round 1
// baseline (948.065 us; speedup 1.0000x reference)
//
#include <hip/hip_runtime.h>
#include <cstdint>

// ---------- types ----------
typedef __bf16 bf16x8 __attribute__((ext_vector_type(8)));
typedef float f32x4 __attribute__((ext_vector_type(4)));
typedef unsigned int u32x4 __attribute__((ext_vector_type(4)));
typedef unsigned short u16x4 __attribute__((ext_vector_type(4)));

#define D_MODEL 1024
#define SEQ     2048
#define NBATCH  4
#define NHEAD   16
#define HDIM    64
#define NTOK    (NBATCH * SEQ)   // 8192

__device__ __forceinline__ unsigned short f2bf(float f) {
  unsigned int u = __builtin_bit_cast(unsigned int, f);
  u += 0x7FFFu + ((u >> 16) & 1u);           // round-to-nearest-even
  return (unsigned short)(u >> 16);
}

__device__ __forceinline__ bf16x8 load8bf(const unsigned short* p) {
  return __builtin_bit_cast(bf16x8, *(const u32x4*)p);
}

__device__ __forceinline__ f32x4 mfma16(bf16x8 a, bf16x8 b, f32x4 c) {
  return __builtin_amdgcn_mfma_f32_16x16x32_bf16(a, b, c, 0, 0, 0);
}

// async global->LDS, 16B per lane; LDS dest must be waveBase + lane*16
__device__ __forceinline__ void gload16(const unsigned short* g, unsigned short* l) {
  __builtin_amdgcn_global_load_lds((__attribute__((address_space(1))) void*)g,
                                   (__attribute__((address_space(3))) void*)l, 16, 0, 0);
}

// ---------- weight cast + transpose: out[n][k] = bf16(in[k][n]) ----------
__global__ __launch_bounds__(256) void tcast(const float* __restrict__ in,
                                             unsigned short* __restrict__ out,
                                             int kbits, int N) {
  const int idx = blockIdx.x * 256 + threadIdx.x;
  const int K = 1 << kbits;
  const int k = idx & (K - 1);
  const int n = idx >> kbits;
  out[((size_t)n << kbits) + k] = f2bf(in[(size_t)k * N + n]);
}

// ---------- layernorm (D=1024), fp32 in -> bf16 out ----------
__global__ __launch_bounds__(256) void ln_kernel(const float* __restrict__ x,
                                                 const float* __restrict__ g,
                                                 const float* __restrict__ bb,
                                                 unsigned short* __restrict__ out) {
  const int row = blockIdx.x, tid = threadIdx.x;
  const float4 xv = ((const float4*)(x + (size_t)row * D_MODEL))[tid];
  float s  = xv.x + xv.y + xv.z + xv.w;
  float ss = xv.x * xv.x + xv.y * xv.y + xv.z * xv.z + xv.w * xv.w;
  #pragma unroll
  for (int off = 1; off < 64; off <<= 1) { s += __shfl_xor(s, off); ss += __shfl_xor(ss, off); }
  __shared__ float red[8];
  const int wave = tid >> 6, lane = tid & 63;
  if (lane == 0) { red[wave] = s; red[4 + wave] = ss; }
  __syncthreads();
  s  = red[0] + red[1] + red[2] + red[3];
  ss = red[4] + red[5] + red[6] + red[7];
  const float mu   = s * (1.0f / D_MODEL);
  const float var  = ss * (1.0f / D_MODEL) - mu * mu;
  const float rstd = rsqrtf(var + 1e-5f);
  const float4 gv = ((const float4*)g)[tid];
  const float4 bv = ((const float4*)bb)[tid];
  u16x4 o;
  o.x = f2bf((xv.x - mu) * rstd * gv.x + bv.x);
  o.y = f2bf((xv.y - mu) * rstd * gv.y + bv.y);
  o.z = f2bf((xv.z - mu) * rstd * gv.z + bv.z);
  o.w = f2bf((xv.w - mu) * rstd * gv.w + bv.w);
  *(u16x4*)(out + (size_t)row * D_MODEL + tid * 4) = o;
}

// ---------- GEMM: C[M,N] = A[M,K](bf16) * Bt[N,K](bf16)^T, 128x128x32 tiles ----------
template <bool BIAS, bool RELU, bool RES, bool OBF>
__global__ __launch_bounds__(256) void gemm_bt(const unsigned short* __restrict__ A,
                                               const unsigned short* __restrict__ Bt,
                                               const float* __restrict__ bias,
                                               const float* __restrict__ res,
                                               void* __restrict__ out,
                                               int M, int N, int K) {
  __shared__ __align__(16) unsigned short As[128 * 32];
  __shared__ __align__(16) unsigned short Bs[128 * 32];
  const int tid  = threadIdx.x;
  const int row0 = blockIdx.y * 128, col0 = blockIdx.x * 128;
  const int wave = tid >> 6, lane = tid & 63;
  const int wm = wave >> 1, wn = wave & 1;
  const int l15 = lane & 15, quad = lane >> 4;
  f32x4 acc[4][4] = {};

  // staging geometry: 512 chunks of 16B; chunk f covers row f/4, cols (f%4)*8..+8
  const int fr = tid >> 2, fc = (tid & 3) * 8;
  const unsigned short* gA  = A  + (size_t)(row0 + fr) * K + fc;
  const unsigned short* gA2 = A  + (size_t)(row0 + 64 + fr) * K + fc;
  const unsigned short* gB  = Bt + (size_t)(col0 + fr) * K + fc;
  const unsigned short* gB2 = Bt + (size_t)(col0 + 64 + fr) * K + fc;
  unsigned short* lA  = As + tid * 8;
  unsigned short* lA2 = As + (tid + 256) * 8;
  unsigned short* lB  = Bs + tid * 8;
  unsigned short* lB2 = Bs + (tid + 256) * 8;

  for (int k0 = 0; k0 < K; k0 += 32) {
    gload16(gA + k0, lA);
    gload16(gA2 + k0, lA2);
    gload16(gB + k0, lB);
    gload16(gB2 + k0, lB2);
    __syncthreads();   // drains vmcnt -> staged data visible
    bf16x8 af[4], bfr[4];
    #pragma unroll
    for (int t = 0; t < 4; ++t) {
      af[t]  = load8bf(As + (wm * 64 + t * 16 + l15) * 32 + quad * 8);
      bfr[t] = load8bf(Bs + (wn * 64 + t * 16 + l15) * 32 + quad * 8);
    }
    #pragma unroll
    for (int i = 0; i < 4; ++i)
      #pragma unroll
      for (int j = 0; j < 4; ++j)
        acc[i][j] = mfma16(af[i], bfr[j], acc[i][j]);
    __syncthreads();   // all reads done before next stage overwrites
  }

  const size_t rbase = (size_t)row0 + wm * 64 + quad * 4;
  const int cbase = col0 + wn * 64 + l15;
  #pragma unroll
  for (int i = 0; i < 4; ++i) {
    #pragma unroll
    for (int j = 0; j < 4; ++j) {
      const int col = cbase + j * 16;
      const float bval = BIAS ? bias[col] : 0.0f;
      #pragma unroll
      for (int r = 0; r < 4; ++r) {
        const size_t row = rbase + i * 16 + r;
        float v = acc[i][j][r];
        if (BIAS) v += bval;
        if (RELU) v = fmaxf(v, 0.0f);
        if (RES)  v += res[row * N + col];
        if (OBF)  ((unsigned short*)out)[row * N + col] = f2bf(v);
        else      ((float*)out)[row * N + col] = v;
      }
    }
  }
}

// ---------- fused causal attention over packed qkv [8192, 3072] bf16 ----------
// grid (T/64, H, B), 256 threads; wave w owns queries qblk*64 + w*16 .. +16
__global__ __launch_bounds__(256) void attn_kernel(const unsigned short* __restrict__ qkv,
                                                   unsigned short* __restrict__ attnb) {
  const int qblk = blockIdx.x, h = blockIdx.y, b = blockIdx.z;
  const int tid = threadIdx.x;
  const int wave = tid >> 6, lane = tid & 63;
  const int l15 = lane & 15, quad = lane >> 4;
  const int qw0 = qblk * 64 + wave * 16;
  const size_t tokbase = (size_t)b * SEQ;

  __shared__ __align__(16) unsigned short vt[HDIM * 32];      // V^T tile: [dim][key]
  __shared__ __align__(16) unsigned short plds[4][16 * 32];   // per-wave P round-trip

  // Q fragments (A-layout), loaded once: rows qw0+l15, dims quad*8..+8 and +32
  const unsigned short* qrow = qkv + (tokbase + qw0 + l15) * 3072 + h * HDIM;
  const bf16x8 qf0 = load8bf(qrow + quad * 8);
  const bf16x8 qf1 = load8bf(qrow + 32 + quad * 8);

  f32x4 acc[4] = {};
  float m_i[4], l_i[4];
  #pragma unroll
  for (int r = 0; r < 4; ++r) { m_i[r] = -__builtin_inff(); l_i[r] = 0.0f; }

  const int ntiles = qblk * 2 + 2;   // block-uniform -> barriers are safe
  for (int kt = 0; kt < ntiles; ++kt) {
    const int k0 = kt * 32;
    __syncthreads();   // previous tile's vt reads complete
    {  // stage V^T: 32 keys x 64 dims
      const int keyl = tid >> 3, d0 = (tid & 7) * 8;
      const unsigned short* vp = qkv + (tokbase + k0 + keyl) * 3072 + 2048 + h * HDIM + d0;
      union { u32x4 v; unsigned short s[8]; } u;
      u.v = *(const u32x4*)vp;
      #pragma unroll
      for (int j = 0; j < 8; ++j) vt[(d0 + j) * 32 + keyl] = u.s[j];
    }
    __syncthreads();
    if (k0 <= qw0 + 15) {   // wave has at least one unmasked key in this tile
      f32x4 s0 = {}, s1 = {};
      const unsigned short* kp0 = qkv + (tokbase + k0 + l15) * 3072 + 1024 + h * HDIM;
      const unsigned short* kp1 = qkv + (tokbase + k0 + 16 + l15) * 3072 + 1024 + h * HDIM;
      s0 = mfma16(qf0, load8bf(kp0 + quad * 8), s0);
      s0 = mfma16(qf1, load8bf(kp0 + 32 + quad * 8), s0);
      s1 = mfma16(qf0, load8bf(kp1 + quad * 8), s1);
      s1 = mfma16(qf1, load8bf(kp1 + 32 + quad * 8), s1);
      #pragma unroll
      for (int r = 0; r < 4; ++r) {
        const int row = qw0 + quad * 4 + r;
        float a0 = s0[r] * 0.125f, a1 = s1[r] * 0.125f;
        if (k0 + l15 > row)      a0 = -__builtin_inff();
        if (k0 + 16 + l15 > row) a1 = -__builtin_inff();
        float mx = fmaxf(a0, a1);
        #pragma unroll
        for (int off = 1; off < 16; off <<= 1) mx = fmaxf(mx, __shfl_xor(mx, off));
        const float mnew  = fmaxf(m_i[r], mx);
        const float alpha = __expf(m_i[r] - mnew);   // exp(-inf - finite)=0 on first tile
        m_i[r] = mnew;
        const float p0 = __expf(a0 - mnew), p1 = __expf(a1 - mnew);
        float prs = p0 + p1;
        #pragma unroll
        for (int off = 1; off < 16; off <<= 1) prs += __shfl_xor(prs, off);
        l_i[r] = l_i[r] * alpha + prs;
        plds[wave][(quad * 4 + r) * 32 + l15]      = f2bf(p0);
        plds[wave][(quad * 4 + r) * 32 + 16 + l15] = f2bf(p1);
        acc[0][r] *= alpha; acc[1][r] *= alpha; acc[2][r] *= alpha; acc[3][r] *= alpha;
      }
      __builtin_amdgcn_s_waitcnt(0);  // wave-local: plds writes -> reads
      const bf16x8 pf = load8bf(&plds[wave][l15 * 32 + quad * 8]);
      #pragma unroll
      for (int d = 0; d < 4; ++d) {
        const bf16x8 vf = load8bf(&vt[(d * 16 + l15) * 32 + quad * 8]);
        acc[d] = mfma16(pf, vf, acc[d]);
      }
    }
  }
  #pragma unroll
  for (int d = 0; d < 4; ++d)
    #pragma unroll
    for (int r = 0; r < 4; ++r) {
      const size_t row = tokbase + qw0 + quad * 4 + r;
      attnb[row * D_MODEL + h * HDIM + d * 16 + l15] = f2bf(acc[d][r] / l_i[r]);
    }
}

// ---------- host ----------
extern "C" void kernel_launch(void* const* d_in, const int* in_sizes, int n_in,
                              void* d_out, int out_size, void* d_ws, size_t ws_size,
                              hipStream_t stream) {
  const float* x    = (const float*)d_in[0];
  const float* wq   = (const float*)d_in[1];
  const float* wk   = (const float*)d_in[2];
  const float* wv   = (const float*)d_in[3];
  const float* wo   = (const float*)d_in[4];
  const float* bo   = (const float*)d_in[5];
  const float* w1   = (const float*)d_in[6];
  const float* b1   = (const float*)d_in[7];
  const float* w2   = (const float*)d_in[8];
  const float* b2   = (const float*)d_in[9];
  const float* g1   = (const float*)d_in[10];
  const float* bl1  = (const float*)d_in[11];
  const float* g2   = (const float*)d_in[12];
  const float* bl2  = (const float*)d_in[13];
  float* out = (float*)d_out;

  char* ws = (char*)d_ws;
  size_t off = 0;
  auto alloc = [&](size_t bytes) { char* p = ws + off; off += (bytes + 255) & ~(size_t)255; return p; };
  unsigned short* wqkv_t = (unsigned short*)alloc((size_t)3072 * 1024 * 2);
  unsigned short* wo_t   = (unsigned short*)alloc((size_t)1024 * 1024 * 2);
  unsigned short* w1_t   = (unsigned short*)alloc((size_t)4096 * 1024 * 2);
  unsigned short* w2_t   = (unsigned short*)alloc((size_t)1024 * 4096 * 2);
  unsigned short* h1     = (unsigned short*)alloc((size_t)NTOK * 1024 * 2);
  unsigned short* qkv    = (unsigned short*)alloc((size_t)NTOK * 3072 * 2);
  unsigned short* attnb  = (unsigned short*)alloc((size_t)NTOK * 1024 * 2);
  unsigned short* h2     = (unsigned short*)alloc((size_t)NTOK * 1024 * 2);
  unsigned short* ffn1   = (unsigned short*)alloc((size_t)NTOK * 4096 * 2);

  // weights -> bf16 [N][K]
  tcast<<<4096, 256, 0, stream>>>(wq, wqkv_t,               10, 1024);
  tcast<<<4096, 256, 0, stream>>>(wk, wqkv_t + 1024 * 1024, 10, 1024);
  tcast<<<4096, 256, 0, stream>>>(wv, wqkv_t + 2048 * 1024, 10, 1024);
  tcast<<<4096, 256, 0, stream>>>(wo, wo_t,                 10, 1024);
  tcast<<<16384, 256, 0, stream>>>(w1, w1_t, 10, 4096);   // -> [4096][1024]
  tcast<<<16384, 256, 0, stream>>>(w2, w2_t, 12, 1024);   // -> [1024][4096]

  // ln1(x) -> h1 (bf16)
  ln_kernel<<<NTOK, 256, 0, stream>>>(x, g1, bl1, h1);
  // qkv = h1 @ [wq|wk|wv]
  gemm_bt<false, false, false, true><<<dim3(24, 64), 256, 0, stream>>>(
      h1, wqkv_t, nullptr, nullptr, qkv, NTOK, 3072, 1024);
  // attention
  attn_kernel<<<dim3(SEQ / 64, NHEAD, NBATCH), 256, 0, stream>>>(qkv, attnb);
  // x1 = x + attn @ wo + bo  -> d_out (fp32)
  gemm_bt<true, false, true, false><<<dim3(8, 64), 256, 0, stream>>>(
      attnb, wo_t, bo, x, out, NTOK, 1024, 1024);
  // ln2(x1) -> h2
  ln_kernel<<<NTOK, 256, 0, stream>>>(out, g2, bl2, h2);
  // ffn1 = relu(h2 @ w1 + b1) (bf16)
  gemm_bt<true, true, false, true><<<dim3(32, 64), 256, 0, stream>>>(
      h2, w1_t, b1, nullptr, ffn1, NTOK, 4096, 1024);
  // out = x1 + ffn1 @ w2 + b2 (fp32, in-place residual from d_out)
  gemm_bt<true, false, true, false><<<dim3(8, 64), 256, 0, stream>>>(
      ffn1, w2_t, b2, out, out, NTOK, 1024, 4096);
  (void)in_sizes; (void)n_in; (void)out_size; (void)ws_size;
}

// Round 2
// 773.318 us; speedup vs baseline: 1.2260x; 1.2260x over previous
//
#include <hip/hip_runtime.h>
#include <cstdint>

// ---------- types ----------
typedef __bf16 bf16x8 __attribute__((ext_vector_type(8)));
typedef float f32x4 __attribute__((ext_vector_type(4)));
typedef unsigned int u32x4 __attribute__((ext_vector_type(4)));
typedef unsigned short u16x4 __attribute__((ext_vector_type(4)));

#define D_MODEL 1024
#define SEQ     2048
#define NBATCH  4
#define NHEAD   16
#define HDIM    64
#define NTOK    (NBATCH * SEQ)   // 8192

__device__ __forceinline__ unsigned short f2bf(float f) {
  unsigned int u = __builtin_bit_cast(unsigned int, f);
  u += 0x7FFFu + ((u >> 16) & 1u);           // round-to-nearest-even
  return (unsigned short)(u >> 16);
}

__device__ __forceinline__ bf16x8 load8bf(const unsigned short* p) {
  return __builtin_bit_cast(bf16x8, *(const u32x4*)p);
}

__device__ __forceinline__ f32x4 mfma16(bf16x8 a, bf16x8 b, f32x4 c) {
  return __builtin_amdgcn_mfma_f32_16x16x32_bf16(a, b, c, 0, 0, 0);
}

// async global->LDS, 16B per lane; LDS dest must be waveBase + lane*16
__device__ __forceinline__ void gload16(const unsigned short* g, unsigned short* l) {
  __builtin_amdgcn_global_load_lds((__attribute__((address_space(1))) void*)g,
                                   (__attribute__((address_space(3))) void*)l, 16, 0, 0);
}

// ---------- weight cast + transpose: out[n][k] = bf16(in[k][n]) ----------
__global__ __launch_bounds__(256) void tcast(const float* __restrict__ in,
                                             unsigned short* __restrict__ out,
                                             int kbits, int N) {
  const int idx = blockIdx.x * 256 + threadIdx.x;
  const int K = 1 << kbits;
  const int k = idx & (K - 1);
  const int n = idx >> kbits;
  out[((size_t)n << kbits) + k] = f2bf(in[(size_t)k * N + n]);
}

// ---------- layernorm (D=1024), fp32 in -> bf16 out ----------
__global__ __launch_bounds__(256) void ln_kernel(const float* __restrict__ x,
                                                 const float* __restrict__ g,
                                                 const float* __restrict__ bb,
                                                 unsigned short* __restrict__ out) {
  const int row = blockIdx.x, tid = threadIdx.x;
  const float4 xv = ((const float4*)(x + (size_t)row * D_MODEL))[tid];
  float s  = xv.x + xv.y + xv.z + xv.w;
  float ss = xv.x * xv.x + xv.y * xv.y + xv.z * xv.z + xv.w * xv.w;
  #pragma unroll
  for (int off = 1; off < 64; off <<= 1) { s += __shfl_xor(s, off); ss += __shfl_xor(ss, off); }
  __shared__ float red[8];
  const int wave = tid >> 6, lane = tid & 63;
  if (lane == 0) { red[wave] = s; red[4 + wave] = ss; }
  __syncthreads();
  s  = red[0] + red[1] + red[2] + red[3];
  ss = red[4] + red[5] + red[6] + red[7];
  const float mu   = s * (1.0f / D_MODEL);
  const float var  = ss * (1.0f / D_MODEL) - mu * mu;
  const float rstd = rsqrtf(var + 1e-5f);
  const float4 gv = ((const float4*)g)[tid];
  const float4 bv = ((const float4*)bb)[tid];
  u16x4 o;
  o.x = f2bf((xv.x - mu) * rstd * gv.x + bv.x);
  o.y = f2bf((xv.y - mu) * rstd * gv.y + bv.y);
  o.z = f2bf((xv.z - mu) * rstd * gv.z + bv.z);
  o.w = f2bf((xv.w - mu) * rstd * gv.w + bv.w);
  *(u16x4*)(out + (size_t)row * D_MODEL + tid * 4) = o;
}

// ---------- GEMM: C[M,N] = A[M,K](bf16) * Bt[N,K](bf16)^T, 128x128x32 tiles ----------
template <bool BIAS, bool RELU, bool RES, bool OBF>
__global__ __launch_bounds__(256) void gemm_bt(const unsigned short* __restrict__ A,
                                               const unsigned short* __restrict__ Bt,
                                               const float* __restrict__ bias,
                                               const float* __restrict__ res,
                                               void* __restrict__ out,
                                               int M, int N, int K) {
  __shared__ __align__(16) unsigned short As[128 * 32];
  __shared__ __align__(16) unsigned short Bs[128 * 32];
  const int tid  = threadIdx.x;
  const int row0 = blockIdx.y * 128, col0 = blockIdx.x * 128;
  const int wave = tid >> 6, lane = tid & 63;
  const int wm = wave >> 1, wn = wave & 1;
  const int l15 = lane & 15, quad = lane >> 4;
  f32x4 acc[4][4] = {};

  const int fr = tid >> 2, fc = (tid & 3) * 8;
  const unsigned short* gA  = A  + (size_t)(row0 + fr) * K + fc;
  const unsigned short* gA2 = A  + (size_t)(row0 + 64 + fr) * K + fc;
  const unsigned short* gB  = Bt + (size_t)(col0 + fr) * K + fc;
  const unsigned short* gB2 = Bt + (size_t)(col0 + 64 + fr) * K + fc;
  unsigned short* lA  = As + tid * 8;
  unsigned short* lA2 = As + (tid + 256) * 8;
  unsigned short* lB  = Bs + tid * 8;
  unsigned short* lB2 = Bs + (tid + 256) * 8;

  for (int k0 = 0; k0 < K; k0 += 32) {
    gload16(gA + k0, lA);
    gload16(gA2 + k0, lA2);
    gload16(gB + k0, lB);
    gload16(gB2 + k0, lB2);
    __syncthreads();
    bf16x8 af[4], bfr[4];
    #pragma unroll
    for (int t = 0; t < 4; ++t) {
      af[t]  = load8bf(As + (wm * 64 + t * 16 + l15) * 32 + quad * 8);
      bfr[t] = load8bf(Bs + (wn * 64 + t * 16 + l15) * 32 + quad * 8);
    }
    #pragma unroll
    for (int i = 0; i < 4; ++i)
      #pragma unroll
      for (int j = 0; j < 4; ++j)
        acc[i][j] = mfma16(af[i], bfr[j], acc[i][j]);
    __syncthreads();
  }

  const size_t rbase = (size_t)row0 + wm * 64 + quad * 4;
  const int cbase = col0 + wn * 64 + l15;
  #pragma unroll
  for (int i = 0; i < 4; ++i) {
    #pragma unroll
    for (int j = 0; j < 4; ++j) {
      const int col = cbase + j * 16;
      const float bval = BIAS ? bias[col] : 0.0f;
      #pragma unroll
      for (int r = 0; r < 4; ++r) {
        const size_t row = rbase + i * 16 + r;
        float v = acc[i][j][r];
        if (BIAS) v += bval;
        if (RELU) v = fmaxf(v, 0.0f);
        if (RES)  v += res[row * N + col];
        if (OBF)  ((unsigned short*)out)[row * N + col] = f2bf(v);
        else      ((float*)out)[row * N + col] = v;
      }
    }
  }
}

// ---------- K/V pre-pack: kp[bh][t][64], vt[bh][64][t] (V transposed) ----------
// grid (SEQ/64, 64); vstage uses 16B-chunk XOR swizzle p = c ^ (tok>>3) so both the
// vector stage-in and the scalar transpose reads are bank-conflict-free.
__global__ __launch_bounds__(256) void kvpack(const unsigned short* __restrict__ qkv,
                                              unsigned short* __restrict__ kp,
                                              unsigned short* __restrict__ vt) {
  const int t0 = blockIdx.x * 64;
  const int bh = blockIdx.y, b = bh >> 4, h = bh & 15;
  const int tid = threadIdx.x, lane = tid & 63, wave = tid >> 6;
  __shared__ __align__(16) unsigned short vstage[64 * 64];
  const size_t qbase = ((size_t)b * SEQ + t0) * 3072;
  #pragma unroll
  for (int i = 0; i < 2; ++i) {      // K: straight copy, coalesced 16B
    const int cid = i * 256 + tid;
    const int r = cid >> 3, c = cid & 7;
    u32x4 vv = *(const u32x4*)(qkv + qbase + (size_t)r * 3072 + 1024 + h * 64 + c * 8);
    *(u32x4*)(kp + ((size_t)bh * SEQ + t0 + r) * 64 + c * 8) = vv;
  }
  #pragma unroll
  for (int i = 0; i < 2; ++i) {      // V: stage with swizzle (source-address side)
    const int cid = i * 256 + tid;
    const int r = cid >> 3, p = cid & 7, c = p ^ (r >> 3);
    gload16(qkv + qbase + (size_t)r * 3072 + 2048 + h * 64 + c * 8, vstage + cid * 8);
  }
  __syncthreads();
  #pragma unroll
  for (int it = 0; it < 2; ++it) {   // transpose out: lane holds dim d, 8 tokens
    const int d = (lane & 7) + wave * 8 + it * 32;
    const int tc = lane >> 3;
    unsigned short tmp[8];
    #pragma unroll
    for (int j = 0; j < 8; ++j) {
      const int tj = tc * 8 + j;
      const int p = (d >> 3) ^ tc;   // chunk of element (tj, d) is d>>3, swizzled by tj>>3
      tmp[j] = vstage[tj * 64 + p * 8 + (d & 7)];
    }
    *(u32x4*)(vt + ((size_t)bh * HDIM + d) * SEQ + t0 + tc * 8) = *(u32x4*)tmp;
  }
}

// ---------- fused causal attention v2 ----------
// 128 queries/block (32/wave), 64-key tiles, K/V staged via global_load_lds with
// chunk-XOR swizzle; P transposed per-wave through swizzled LDS.
__global__ __launch_bounds__(256) void attn2(const unsigned short* __restrict__ qkv,
                                             const unsigned short* __restrict__ kp,
                                             const unsigned short* __restrict__ vt,
                                             unsigned short* __restrict__ attnb) {
  const int qblk = gridDim.x - 1 - blockIdx.x;   // heavy blocks dispatch first
  const int h = blockIdx.y, b = blockIdx.z, bh = b * NHEAD + h;
  const int tid = threadIdx.x, wave = tid >> 6, lane = tid & 63;
  const int l15 = lane & 15, quad = lane >> 4;
  const int q0 = qblk * 128, qw0 = q0 + wave * 32;
  const size_t tokbase = (size_t)b * SEQ;

  __shared__ __align__(16) unsigned short ks[64 * 64];       // [key][dim], chunk-swizzled
  __shared__ __align__(16) unsigned short vts[64 * 64];      // [dim][key], chunk-swizzled
  __shared__ __align__(16) unsigned short plds[4][32 * 64];  // per-wave P, swizzled

  // Q a-frags (held all kernel): rows qw0+mf*16+l15, dims kf*32+quad*8..+8
  bf16x8 qf[2][2];
  #pragma unroll
  for (int mf = 0; mf < 2; ++mf)
    #pragma unroll
    for (int kf = 0; kf < 2; ++kf)
      qf[mf][kf] = load8bf(qkv + (tokbase + qw0 + mf * 16 + l15) * 3072 + h * HDIM + kf * 32 + quad * 8);

  f32x4 o[2][4] = {};
  float m_i[2][4], l_i[2][4];
  #pragma unroll
  for (int mf = 0; mf < 2; ++mf)
    #pragma unroll
    for (int r = 0; r < 4; ++r) { m_i[mf][r] = -__builtin_inff(); l_i[mf][r] = 0.0f; }

  const unsigned short* kbase = kp + (size_t)bh * SEQ * HDIM;
  const unsigned short* vbase = vt + (size_t)bh * HDIM * SEQ;

  const int ntiles = qblk * 2 + 2;
  for (int kt = 0; kt < ntiles; ++kt) {
    const int k0 = kt * 64;
    __syncthreads();                       // previous tile fully consumed
    #pragma unroll
    for (int i = 0; i < 2; ++i) {          // stage K tile (8KB)
      const int cid = i * 256 + tid;
      const int r = cid >> 3, p = cid & 7, c = p ^ (r & 7);
      gload16(kbase + (size_t)(k0 + r) * HDIM + c * 8, ks + cid * 8);
    }
    #pragma unroll
    for (int i = 0; i < 2; ++i) {          // stage V^T tile (8KB)
      const int cid = i * 256 + tid;
      const int d = cid >> 3, p = cid & 7, c = p ^ (d & 7);
      gload16(vbase + (size_t)d * SEQ + k0 + c * 8, vts + cid * 8);
    }
    __syncthreads();                       // implicit vmcnt(0) drain -> data visible
    if (k0 <= qw0 + 31) {
      // ---- QK^T: 16 MFMAs ----
      f32x4 s[2][4] = {};
      #pragma unroll
      for (int kf = 0; kf < 2; ++kf)
        #pragma unroll
        for (int nf = 0; nf < 4; ++nf) {
          const int row = nf * 16 + l15;                     // key (local)
          const int p = (kf * 4 + quad) ^ (row & 7);
          const bf16x8 bk = load8bf(ks + row * 64 + p * 8);
          s[0][nf] = mfma16(qf[0][kf], bk, s[0][nf]);
          s[1][nf] = mfma16(qf[1][kf], bk, s[1][nf]);
        }
      // ---- online softmax + P store ----
      #pragma unroll
      for (int mf = 0; mf < 2; ++mf)
        #pragma unroll
        for (int r = 0; r < 4; ++r) {
          const int lq = mf * 16 + quad * 4 + r;             // local query (0..31)
          const int q = qw0 + lq;                            // seq query
          float a[4];
          #pragma unroll
          for (int nf = 0; nf < 4; ++nf) {
            a[nf] = s[mf][nf][r] * 0.125f;
            if (k0 + nf * 16 + l15 > q) a[nf] = -__builtin_inff();
          }
          float mx = fmaxf(fmaxf(a[0], a[1]), fmaxf(a[2], a[3]));
          #pragma unroll
          for (int off = 1; off < 16; off <<= 1) mx = fmaxf(mx, __shfl_xor(mx, off));
          const float mnew  = fmaxf(m_i[mf][r], mx);
          const float alpha = __expf(m_i[mf][r] - mnew);
          m_i[mf][r] = mnew;
          float ps = 0.0f;
          #pragma unroll
          for (int nf = 0; nf < 4; ++nf) {
            const float pv = __expf(a[nf] - mnew);
            ps += pv;
            const int key = nf * 16 + l15;
            const int p = (key >> 3) ^ (lq & 7) ^ ((lq >> 3) & 3);
            plds[wave][lq * 64 + p * 8 + (key & 7)] = f2bf(pv);
          }
          #pragma unroll
          for (int off = 1; off < 16; off <<= 1) ps += __shfl_xor(ps, off);
          l_i[mf][r] = l_i[mf][r] * alpha + ps;
          #pragma unroll
          for (int df = 0; df < 4; ++df) o[mf][df][r] *= alpha;
        }
      __builtin_amdgcn_s_waitcnt(0);       // wave-local plds writes -> reads
      // ---- PV: 16 MFMAs ----
      #pragma unroll
      for (int kf = 0; kf < 2; ++kf) {
        bf16x8 pa[2];
        #pragma unroll
        for (int mf = 0; mf < 2; ++mf) {
          const int lq = mf * 16 + l15;
          const int p = (kf * 4 + quad) ^ (lq & 7) ^ ((lq >> 3) & 3);
          pa[mf] = load8bf(&plds[wave][lq * 64 + p * 8]);
        }
        #pragma unroll
        for (int df = 0; df < 4; ++df) {
          const int row = df * 16 + l15;                     // dim (local)
          const int p = (kf * 4 + quad) ^ (row & 7);
          const bf16x8 vb = load8bf(vts + row * 64 + p * 8);
          o[0][df] = mfma16(pa[0], vb, o[0][df]);
          o[1][df] = mfma16(pa[1], vb, o[1][df]);
        }
      }
    }
  }
  #pragma unroll
  for (int mf = 0; mf < 2; ++mf)
    #pragma unroll
    for (int df = 0; df < 4; ++df)
      #pragma unroll
      for (int r = 0; r < 4; ++r) {
        const size_t row = tokbase + qw0 + mf * 16 + quad * 4 + r;
        attnb[row * D_MODEL + h * HDIM + df * 16 + l15] = f2bf(o[mf][df][r] / l_i[mf][r]);
      }
}

// ---------- host ----------
extern "C" void kernel_launch(void* const* d_in, const int* in_sizes, int n_in,
                              void* d_out, int out_size, void* d_ws, size_t ws_size,
                              hipStream_t stream) {
  const float* x    = (const float*)d_in[0];
  const float* wq   = (const float*)d_in[1];
  const float* wk   = (const float*)d_in[2];
  const float* wv   = (const float*)d_in[3];
  const float* wo   = (const float*)d_in[4];
  const float* bo   = (const float*)d_in[5];
  const float* w1   = (const float*)d_in[6];
  const float* b1   = (const float*)d_in[7];
  const float* w2   = (const float*)d_in[8];
  const float* b2   = (const float*)d_in[9];
  const float* g1   = (const float*)d_in[10];
  const float* bl1  = (const float*)d_in[11];
  const float* g2   = (const float*)d_in[12];
  const float* bl2  = (const float*)d_in[13];
  float* out = (float*)d_out;

  char* ws = (char*)d_ws;
  size_t off = 0;
  auto alloc = [&](size_t bytes) { char* p = ws + off; off += (bytes + 255) & ~(size_t)255; return p; };
  unsigned short* wqkv_t = (unsigned short*)alloc((size_t)3072 * 1024 * 2);
  unsigned short* wo_t   = (unsigned short*)alloc((size_t)1024 * 1024 * 2);
  unsigned short* w1_t   = (unsigned short*)alloc((size_t)4096 * 1024 * 2);
  unsigned short* w2_t   = (unsigned short*)alloc((size_t)1024 * 4096 * 2);
  unsigned short* h1     = (unsigned short*)alloc((size_t)NTOK * 1024 * 2);
  unsigned short* qkv    = (unsigned short*)alloc((size_t)NTOK * 3072 * 2);
  unsigned short* attnb  = (unsigned short*)alloc((size_t)NTOK * 1024 * 2);
  unsigned short* h2     = (unsigned short*)alloc((size_t)NTOK * 1024 * 2);
  unsigned short* ffn1   = (unsigned short*)alloc((size_t)NTOK * 4096 * 2);
  // Aliases (no extra ws): kp reuses h1 (dead after QKV GEMM);
  // vtb reuses h2 (ln2 writes h2 only after attention completes).
  unsigned short* kpb = h1;   // [64][2048][64] bf16 = 16.78 MB == sizeof(h1)
  unsigned short* vtb = h2;   // [64][64][2048] bf16 = 16.78 MB == sizeof(h2)

  tcast<<<4096, 256, 0, stream>>>(wq, wqkv_t,               10, 1024);
  tcast<<<4096, 256, 0, stream>>>(wk, wqkv_t + 1024 * 1024, 10, 1024);
  tcast<<<4096, 256, 0, stream>>>(wv, wqkv_t + 2048 * 1024, 10, 1024);
  tcast<<<4096, 256, 0, stream>>>(wo, wo_t,                 10, 1024);
  tcast<<<16384, 256, 0, stream>>>(w1, w1_t, 10, 4096);
  tcast<<<16384, 256, 0, stream>>>(w2, w2_t, 12, 1024);

  ln_kernel<<<NTOK, 256, 0, stream>>>(x, g1, bl1, h1);
  gemm_bt<false, false, false, true><<<dim3(24, 64), 256, 0, stream>>>(
      h1, wqkv_t, nullptr, nullptr, qkv, NTOK, 3072, 1024);
  kvpack<<<dim3(SEQ / 64, NBATCH * NHEAD), 256, 0, stream>>>(qkv, kpb, vtb);
  attn2<<<dim3(SEQ / 128, NHEAD, NBATCH), 256, 0, stream>>>(qkv, kpb, vtb, attnb);
  gemm_bt<true, false, true, false><<<dim3(8, 64), 256, 0, stream>>>(
      attnb, wo_t, bo, x, out, NTOK, 1024, 1024);
  ln_kernel<<<NTOK, 256, 0, stream>>>(out, g2, bl2, h2);
  gemm_bt<true, true, false, true><<<dim3(32, 64), 256, 0, stream>>>(
      h2, w1_t, b1, nullptr, ffn1, NTOK, 4096, 1024);
  gemm_bt<true, false, true, false><<<dim3(8, 64), 256, 0, stream>>>(
      ffn1, w2_t, b2, out, out, NTOK, 1024, 4096);
  (void)in_sizes; (void)n_in; (void)out_size; (void)ws_size;
}

// Round 3
// 625.775 us; speedup vs baseline: 1.5150x; 1.2358x over previous
//
#include <hip/hip_runtime.h>
#include <cstdint>

// ---------- types ----------
typedef __bf16 bf16x8 __attribute__((ext_vector_type(8)));
typedef float f32x4 __attribute__((ext_vector_type(4)));
typedef unsigned int u32x4 __attribute__((ext_vector_type(4)));
typedef unsigned short u16x4 __attribute__((ext_vector_type(4)));

#define D_MODEL 1024
#define SEQ     2048
#define NBATCH  4
#define NHEAD   16
#define HDIM    64
#define NTOK    (NBATCH * SEQ)   // 8192

__device__ __forceinline__ unsigned short f2bf(float f) {
  unsigned int u = __builtin_bit_cast(unsigned int, f);
  u += 0x7FFFu + ((u >> 16) & 1u);           // round-to-nearest-even
  return (unsigned short)(u >> 16);
}

__device__ __forceinline__ bf16x8 load8bf(const unsigned short* p) {
  return __builtin_bit_cast(bf16x8, *(const u32x4*)p);
}

__device__ __forceinline__ f32x4 mfma16(bf16x8 a, bf16x8 b, f32x4 c) {
  return __builtin_amdgcn_mfma_f32_16x16x32_bf16(a, b, c, 0, 0, 0);
}

// async global->LDS, 16B per lane; LDS dest must be waveBase + lane*16
__device__ __forceinline__ void gload16(const unsigned short* g, unsigned short* l) {
  __builtin_amdgcn_global_load_lds((__attribute__((address_space(1))) void*)g,
                                   (__attribute__((address_space(3))) void*)l, 16, 0, 0);
}

// scale a bf16x8 fragment by s (round-to-nearest), used once per kernel for Q
__device__ __forceinline__ bf16x8 scale8(bf16x8 v, float s) {
  u32x4 u = __builtin_bit_cast(u32x4, v);
  unsigned short out[8];
  #pragma unroll
  for (int i = 0; i < 4; ++i) {
    unsigned int w = u[i];
    float lo = __builtin_bit_cast(float, w << 16) * s;
    float hi = __builtin_bit_cast(float, w & 0xFFFF0000u) * s;
    out[2 * i]     = f2bf(lo);
    out[2 * i + 1] = f2bf(hi);
  }
  return __builtin_bit_cast(bf16x8, *(u32x4*)out);
}

// ---------- weight cast + transpose: out[n][k] = bf16(in[k][n]) ----------
__global__ __launch_bounds__(256) void tcast(const float* __restrict__ in,
                                             unsigned short* __restrict__ out,
                                             int kbits, int N) {
  const int idx = blockIdx.x * 256 + threadIdx.x;
  const int K = 1 << kbits;
  const int k = idx & (K - 1);
  const int n = idx >> kbits;
  out[((size_t)n << kbits) + k] = f2bf(in[(size_t)k * N + n]);
}

// ---------- layernorm (D=1024), fp32 in -> bf16 out ----------
__global__ __launch_bounds__(256) void ln_kernel(const float* __restrict__ x,
                                                 const float* __restrict__ g,
                                                 const float* __restrict__ bb,
                                                 unsigned short* __restrict__ out) {
  const int row = blockIdx.x, tid = threadIdx.x;
  const float4 xv = ((const float4*)(x + (size_t)row * D_MODEL))[tid];
  float s  = xv.x + xv.y + xv.z + xv.w;
  float ss = xv.x * xv.x + xv.y * xv.y + xv.z * xv.z + xv.w * xv.w;
  #pragma unroll
  for (int off = 1; off < 64; off <<= 1) { s += __shfl_xor(s, off); ss += __shfl_xor(ss, off); }
  __shared__ float red[8];
  const int wave = tid >> 6, lane = tid & 63;
  if (lane == 0) { red[wave] = s; red[4 + wave] = ss; }
  __syncthreads();
  s  = red[0] + red[1] + red[2] + red[3];
  ss = red[4] + red[5] + red[6] + red[7];
  const float mu   = s * (1.0f / D_MODEL);
  const float var  = ss * (1.0f / D_MODEL) - mu * mu;
  const float rstd = rsqrtf(var + 1e-5f);
  const float4 gv = ((const float4*)g)[tid];
  const float4 bv = ((const float4*)bb)[tid];
  u16x4 o;
  o.x = f2bf((xv.x - mu) * rstd * gv.x + bv.x);
  o.y = f2bf((xv.y - mu) * rstd * gv.y + bv.y);
  o.z = f2bf((xv.z - mu) * rstd * gv.z + bv.z);
  o.w = f2bf((xv.w - mu) * rstd * gv.w + bv.w);
  *(u16x4*)(out + (size_t)row * D_MODEL + tid * 4) = o;
}

// ---------- GEMM: C[M,N] = A[M,K](bf16) * Bt[N,K](bf16)^T, 128x128x32 tiles ----------
template <bool BIAS, bool RELU, bool RES, bool OBF>
__global__ __launch_bounds__(256) void gemm_bt(const unsigned short* __restrict__ A,
                                               const unsigned short* __restrict__ Bt,
                                               const float* __restrict__ bias,
                                               const float* __restrict__ res,
                                               void* __restrict__ out,
                                               int M, int N, int K) {
  __shared__ __align__(16) unsigned short As[128 * 32];
  __shared__ __align__(16) unsigned short Bs[128 * 32];
  const int tid  = threadIdx.x;
  const int row0 = blockIdx.y * 128, col0 = blockIdx.x * 128;
  const int wave = tid >> 6, lane = tid & 63;
  const int wm = wave >> 1, wn = wave & 1;
  const int l15 = lane & 15, quad = lane >> 4;
  f32x4 acc[4][4] = {};

  const int fr = tid >> 2, fc = (tid & 3) * 8;
  const unsigned short* gA  = A  + (size_t)(row0 + fr) * K + fc;
  const unsigned short* gA2 = A  + (size_t)(row0 + 64 + fr) * K + fc;
  const unsigned short* gB  = Bt + (size_t)(col0 + fr) * K + fc;
  const unsigned short* gB2 = Bt + (size_t)(col0 + 64 + fr) * K + fc;
  unsigned short* lA  = As + tid * 8;
  unsigned short* lA2 = As + (tid + 256) * 8;
  unsigned short* lB  = Bs + tid * 8;
  unsigned short* lB2 = Bs + (tid + 256) * 8;

  for (int k0 = 0; k0 < K; k0 += 32) {
    gload16(gA + k0, lA);
    gload16(gA2 + k0, lA2);
    gload16(gB + k0, lB);
    gload16(gB2 + k0, lB2);
    __syncthreads();
    bf16x8 af[4], bfr[4];
    #pragma unroll
    for (int t = 0; t < 4; ++t) {
      af[t]  = load8bf(As + (wm * 64 + t * 16 + l15) * 32 + quad * 8);
      bfr[t] = load8bf(Bs + (wn * 64 + t * 16 + l15) * 32 + quad * 8);
    }
    #pragma unroll
    for (int i = 0; i < 4; ++i)
      #pragma unroll
      for (int j = 0; j < 4; ++j)
        acc[i][j] = mfma16(af[i], bfr[j], acc[i][j]);
    __syncthreads();
  }

  const size_t rbase = (size_t)row0 + wm * 64 + quad * 4;
  const int cbase = col0 + wn * 64 + l15;
  #pragma unroll
  for (int i = 0; i < 4; ++i) {
    #pragma unroll
    for (int j = 0; j < 4; ++j) {
      const int col = cbase + j * 16;
      const float bval = BIAS ? bias[col] : 0.0f;
      #pragma unroll
      for (int r = 0; r < 4; ++r) {
        const size_t row = rbase + i * 16 + r;
        float v = acc[i][j][r];
        if (BIAS) v += bval;
        if (RELU) v = fmaxf(v, 0.0f);
        if (RES)  v += res[row * N + col];
        if (OBF)  ((unsigned short*)out)[row * N + col] = f2bf(v);
        else      ((float*)out)[row * N + col] = v;
      }
    }
  }
}

// ---------- K/V pre-pack: kp[bh][t][64], vt[bh][64][t] (V transposed) ----------
__global__ __launch_bounds__(256) void kvpack(const unsigned short* __restrict__ qkv,
                                              unsigned short* __restrict__ kp,
                                              unsigned short* __restrict__ vt) {
  const int t0 = blockIdx.x * 64;
  const int bh = blockIdx.y, b = bh >> 4, h = bh & 15;
  const int tid = threadIdx.x, lane = tid & 63, wave = tid >> 6;
  __shared__ __align__(16) unsigned short vstage[64 * 64];
  const size_t qbase = ((size_t)b * SEQ + t0) * 3072;
  #pragma unroll
  for (int i = 0; i < 2; ++i) {      // K: straight copy, coalesced 16B
    const int cid = i * 256 + tid;
    const int r = cid >> 3, c = cid & 7;
    u32x4 vv = *(const u32x4*)(qkv + qbase + (size_t)r * 3072 + 1024 + h * 64 + c * 8);
    *(u32x4*)(kp + ((size_t)bh * SEQ + t0 + r) * 64 + c * 8) = vv;
  }
  #pragma unroll
  for (int i = 0; i < 2; ++i) {      // V: stage with chunk-XOR swizzle
    const int cid = i * 256 + tid;
    const int r = cid >> 3, p = cid & 7, c = p ^ (r >> 3);
    gload16(qkv + qbase + (size_t)r * 3072 + 2048 + h * 64 + c * 8, vstage + cid * 8);
  }
  __syncthreads();
  #pragma unroll
  for (int it = 0; it < 2; ++it) {   // transpose out: lane holds dim d, 8 tokens
    const int d = (lane & 7) + wave * 8 + it * 32;
    const int tc = lane >> 3;
    unsigned short tmp[8];
    #pragma unroll
    for (int j = 0; j < 8; ++j) {
      const int tj = tc * 8 + j;
      const int p = (d >> 3) ^ tc;
      tmp[j] = vstage[tj * 64 + p * 8 + (d & 7)];
    }
    *(u32x4*)(vt + ((size_t)bh * HDIM + d) * SEQ + t0 + tc * 8) = *(u32x4*)tmp;
  }
}

// ---------- fused causal attention v3 ----------
// Fixed-max softmax (scores bounded, softmax shift-invariant): no running max,
// no alpha rescale, no per-tile shuffles. Q pre-scaled by 0.125*log2(e) so the
// QK^T MFMA output feeds exp2 directly. Triangle pairing: block x does qblk
// (15-x) then x -> uniform 34 tiles/block, 512 blocks, no straggler decay.
__global__ __launch_bounds__(256) void attn3(const unsigned short* __restrict__ qkv,
                                             const unsigned short* __restrict__ kp,
                                             const unsigned short* __restrict__ vt,
                                             unsigned short* __restrict__ attnb) {
  const int h = blockIdx.y, b = blockIdx.z, bh = b * NHEAD + h;
  const int tid = threadIdx.x, wave = tid >> 6, lane = tid & 63;
  const int l15 = lane & 15, quad = lane >> 4;
  const size_t tokbase = (size_t)b * SEQ;

  __shared__ __align__(16) unsigned short ks[64 * 64];       // [key][dim], chunk-swizzled
  __shared__ __align__(16) unsigned short vts[64 * 64];      // [dim][key], chunk-swizzled
  __shared__ __align__(16) unsigned short plds[4][32 * 64];  // per-wave P, swizzled

  const unsigned short* kbase = kp + (size_t)bh * SEQ * HDIM;
  const unsigned short* vbase = vt + (size_t)bh * HDIM * SEQ;
  const float qscale = 0.18033688011112042f;   // 0.125 * log2(e)

  for (int half = 0; half < 2; ++half) {
    const int qblk = (half == 0) ? (15 - blockIdx.x) : blockIdx.x;
    const int qw0 = qblk * 128 + wave * 32;

    bf16x8 qf[2][2];
    #pragma unroll
    for (int mf = 0; mf < 2; ++mf)
      #pragma unroll
      for (int kf = 0; kf < 2; ++kf)
        qf[mf][kf] = scale8(load8bf(qkv + (tokbase + qw0 + mf * 16 + l15) * 3072
                                    + h * HDIM + kf * 32 + quad * 8), qscale);

    f32x4 o[2][4] = {};
    float lsum[2][4] = {};

    const int ntiles = qblk * 2 + 2;
    for (int kt = 0; kt < ntiles; ++kt) {
      const int k0 = kt * 64;
      __syncthreads();                       // previous tile fully consumed
      #pragma unroll
      for (int i = 0; i < 2; ++i) {          // stage K tile (8KB)
        const int cid = i * 256 + tid;
        const int r = cid >> 3, p = cid & 7, c = p ^ (r & 7);
        gload16(kbase + (size_t)(k0 + r) * HDIM + c * 8, ks + cid * 8);
      }
      #pragma unroll
      for (int i = 0; i < 2; ++i) {          // stage V^T tile (8KB)
        const int cid = i * 256 + tid;
        const int d = cid >> 3, p = cid & 7, c = p ^ (d & 7);
        gload16(vbase + (size_t)d * SEQ + k0 + c * 8, vts + cid * 8);
      }
      __syncthreads();                       // vmcnt drain -> staged data visible
      if (k0 <= qw0 + 31) {
        // ---- QK^T: 16 MFMAs ----
        f32x4 s[2][4] = {};
        #pragma unroll
        for (int kf = 0; kf < 2; ++kf)
          #pragma unroll
          for (int nf = 0; nf < 4; ++nf) {
            const int row = nf * 16 + l15;
            const int p = (kf * 4 + quad) ^ (row & 7);
            const bf16x8 bk = load8bf(ks + row * 64 + p * 8);
            s[0][nf] = mfma16(qf[0][kf], bk, s[0][nf]);
            s[1][nf] = mfma16(qf[1][kf], bk, s[1][nf]);
          }
        // ---- fixed-max softmax: p = exp2(s), mask, accumulate l, store P ----
        #pragma unroll
        for (int mf = 0; mf < 2; ++mf)
          #pragma unroll
          for (int nf = 0; nf < 4; ++nf) {
            const int key = k0 + nf * 16 + l15;
            #pragma unroll
            for (int r = 0; r < 4; ++r) {
              const int lq = mf * 16 + quad * 4 + r;
              float p = __builtin_amdgcn_exp2f(s[mf][nf][r]);
              p = (key > qw0 + lq) ? 0.0f : p;
              const unsigned int pu = __builtin_bit_cast(unsigned int, p);
              lsum[mf][r] += __builtin_bit_cast(float, pu & 0xFFFF0000u);  // match stored P
              const int pc = ((nf * 16 + l15) >> 3) ^ (lq & 7) ^ ((lq >> 3) & 3);
              plds[wave][lq * 64 + pc * 8 + (l15 & 7)] = (unsigned short)(pu >> 16);
            }
          }
        __builtin_amdgcn_s_waitcnt(0);       // wave-local plds writes -> reads
        // ---- PV: 16 MFMAs ----
        #pragma unroll
        for (int kf = 0; kf < 2; ++kf) {
          bf16x8 pa[2];
          #pragma unroll
          for (int mf = 0; mf < 2; ++mf) {
            const int lq = mf * 16 + l15;
            const int p = (kf * 4 + quad) ^ (lq & 7) ^ ((lq >> 3) & 3);
            pa[mf] = load8bf(&plds[wave][lq * 64 + p * 8]);
          }
          #pragma unroll
          for (int df = 0; df < 4; ++df) {
            const int row = df * 16 + l15;
            const int p = (kf * 4 + quad) ^ (row & 7);
            const bf16x8 vb = load8bf(vts + row * 64 + p * 8);
            o[0][df] = mfma16(pa[0], vb, o[0][df]);
            o[1][df] = mfma16(pa[1], vb, o[1][df]);
          }
        }
      }
    }
    // ---- normalize + write (one butterfly per row, once per half) ----
    #pragma unroll
    for (int mf = 0; mf < 2; ++mf)
      #pragma unroll
      for (int r = 0; r < 4; ++r) {
        float l = lsum[mf][r];
        #pragma unroll
        for (int off = 1; off < 16; off <<= 1) l += __shfl_xor(l, off);
        const float rl = 1.0f / l;
        const size_t row = tokbase + qw0 + mf * 16 + quad * 4 + r;
        #pragma unroll
        for (int df = 0; df < 4; ++df)
          attnb[row * D_MODEL + h * HDIM + df * 16 + l15] = f2bf(o[mf][df][r] * rl);
      }
  }
}

// ---------- host ----------
extern "C" void kernel_launch(void* const* d_in, const int* in_sizes, int n_in,
                              void* d_out, int out_size, void* d_ws, size_t ws_size,
                              hipStream_t stream) {
  const float* x    = (const float*)d_in[0];
  const float* wq   = (const float*)d_in[1];
  const float* wk   = (const float*)d_in[2];
  const float* wv   = (const float*)d_in[3];
  const float* wo   = (const float*)d_in[4];
  const float* bo   = (const float*)d_in[5];
  const float* w1   = (const float*)d_in[6];
  const float* b1   = (const float*)d_in[7];
  const float* w2   = (const float*)d_in[8];
  const float* b2   = (const float*)d_in[9];
  const float* g1   = (const float*)d_in[10];
  const float* bl1  = (const float*)d_in[11];
  const float* g2   = (const float*)d_in[12];
  const float* bl2  = (const float*)d_in[13];
  float* out = (float*)d_out;

  char* ws = (char*)d_ws;
  size_t off = 0;
  auto alloc = [&](size_t bytes) { char* p = ws + off; off += (bytes + 255) & ~(size_t)255; return p; };
  unsigned short* wqkv_t = (unsigned short*)alloc((size_t)3072 * 1024 * 2);
  unsigned short* wo_t   = (unsigned short*)alloc((size_t)1024 * 1024 * 2);
  unsigned short* w1_t   = (unsigned short*)alloc((size_t)4096 * 1024 * 2);
  unsigned short* w2_t   = (unsigned short*)alloc((size_t)1024 * 4096 * 2);
  unsigned short* h1     = (unsigned short*)alloc((size_t)NTOK * 1024 * 2);
  unsigned short* qkv    = (unsigned short*)alloc((size_t)NTOK * 3072 * 2);
  unsigned short* attnb  = (unsigned short*)alloc((size_t)NTOK * 1024 * 2);
  unsigned short* h2     = (unsigned short*)alloc((size_t)NTOK * 1024 * 2);
  unsigned short* ffn1   = (unsigned short*)alloc((size_t)NTOK * 4096 * 2);
  unsigned short* kpb = h1;   // alias: dead after QKV GEMM
  unsigned short* vtb = h2;   // alias: ln2 writes h2 after attention completes

  tcast<<<4096, 256, 0, stream>>>(wq, wqkv_t,               10, 1024);
  tcast<<<4096, 256, 0, stream>>>(wk, wqkv_t + 1024 * 1024, 10, 1024);
  tcast<<<4096, 256, 0, stream>>>(wv, wqkv_t + 2048 * 1024, 10, 1024);
  tcast<<<4096, 256, 0, stream>>>(wo, wo_t,                 10, 1024);
  tcast<<<16384, 256, 0, stream>>>(w1, w1_t, 10, 4096);
  tcast<<<16384, 256, 0, stream>>>(w2, w2_t, 12, 1024);

  ln_kernel<<<NTOK, 256, 0, stream>>>(x, g1, bl1, h1);
  gemm_bt<false, false, false, true><<<dim3(24, 64), 256, 0, stream>>>(
      h1, wqkv_t, nullptr, nullptr, qkv, NTOK, 3072, 1024);
  kvpack<<<dim3(SEQ / 64, NBATCH * NHEAD), 256, 0, stream>>>(qkv, kpb, vtb);
  attn3<<<dim3(SEQ / 256, NHEAD, NBATCH), 256, 0, stream>>>(qkv, kpb, vtb, attnb);
  gemm_bt<true, false, true, false><<<dim3(8, 64), 256, 0, stream>>>(
      attnb, wo_t, bo, x, out, NTOK, 1024, 1024);
  ln_kernel<<<NTOK, 256, 0, stream>>>(out, g2, bl2, h2);
  gemm_bt<true, true, false, true><<<dim3(32, 64), 256, 0, stream>>>(
      h2, w1_t, b1, nullptr, ffn1, NTOK, 4096, 1024);
  gemm_bt<true, false, true, false><<<dim3(8, 64), 256, 0, stream>>>(
      ffn1, w2_t, b2, out, out, NTOK, 1024, 4096);
  (void)in_sizes; (void)n_in; (void)out_size; (void)ws_size;
}

// Round 4
// 537.598 us; speedup vs baseline: 1.7635x; 1.1640x over previous
//
#include <hip/hip_runtime.h>
#include <cstdint>

// ---------- types ----------
typedef __bf16 bf16x8 __attribute__((ext_vector_type(8)));
typedef float f32x4 __attribute__((ext_vector_type(4)));
typedef unsigned int u32x4 __attribute__((ext_vector_type(4)));
typedef unsigned short u16x4 __attribute__((ext_vector_type(4)));

#define D_MODEL 1024
#define SEQ     2048
#define NBATCH  4
#define NHEAD   16
#define HDIM    64
#define NTOK    (NBATCH * SEQ)   // 8192

__device__ __forceinline__ unsigned short f2bf(float f) {
  unsigned int u = __builtin_bit_cast(unsigned int, f);
  u += 0x7FFFu + ((u >> 16) & 1u);           // round-to-nearest-even
  return (unsigned short)(u >> 16);
}

__device__ __forceinline__ bf16x8 load8bf(const unsigned short* p) {
  return __builtin_bit_cast(bf16x8, *(const u32x4*)p);
}

__device__ __forceinline__ f32x4 mfma16(bf16x8 a, bf16x8 b, f32x4 c) {
  return __builtin_amdgcn_mfma_f32_16x16x32_bf16(a, b, c, 0, 0, 0);
}

// async global->LDS, 16B per lane; LDS dest must be waveBase + lane*16
__device__ __forceinline__ void gload16(const unsigned short* g, unsigned short* l) {
  __builtin_amdgcn_global_load_lds((__attribute__((address_space(1))) void*)g,
                                   (__attribute__((address_space(3))) void*)l, 16, 0, 0);
}

// scale a bf16x8 fragment by s (round-to-nearest), used once per kernel for Q
__device__ __forceinline__ bf16x8 scale8(bf16x8 v, float s) {
  u32x4 u = __builtin_bit_cast(u32x4, v);
  unsigned short out[8];
  #pragma unroll
  for (int i = 0; i < 4; ++i) {
    unsigned int w = u[i];
    float lo = __builtin_bit_cast(float, w << 16) * s;
    float hi = __builtin_bit_cast(float, w & 0xFFFF0000u) * s;
    out[2 * i]     = f2bf(lo);
    out[2 * i + 1] = f2bf(hi);
  }
  return __builtin_bit_cast(bf16x8, *(u32x4*)out);
}

// ---------- transposing weight cast: out[n][k] = bf16(in[k][n]), LDS-tiled ----------
__global__ __launch_bounds__(256) void tcastT(const float* __restrict__ in,
                                              unsigned short* __restrict__ out,
                                              int K, int N) {
  __shared__ float tile[32][33];
  const int k0 = blockIdx.y * 32, n0 = blockIdx.x * 32;
  const int tx = threadIdx.x & 31, ty = threadIdx.x >> 5;   // ty 0..7
  #pragma unroll
  for (int j = 0; j < 4; ++j)
    tile[ty + 8 * j][tx] = in[(size_t)(k0 + ty + 8 * j) * N + n0 + tx];
  __syncthreads();
  #pragma unroll
  for (int j = 0; j < 4; ++j)
    out[(size_t)(n0 + ty + 8 * j) * K + k0 + tx] = f2bf(tile[tx][ty + 8 * j]);
}

// ---------- layernorm (D=1024), fp32 in -> bf16 out ----------
__global__ __launch_bounds__(256) void ln_kernel(const float* __restrict__ x,
                                                 const float* __restrict__ g,
                                                 const float* __restrict__ bb,
                                                 unsigned short* __restrict__ out) {
  const int row = blockIdx.x, tid = threadIdx.x;
  const float4 xv = ((const float4*)(x + (size_t)row * D_MODEL))[tid];
  float s  = xv.x + xv.y + xv.z + xv.w;
  float ss = xv.x * xv.x + xv.y * xv.y + xv.z * xv.z + xv.w * xv.w;
  #pragma unroll
  for (int off = 1; off < 64; off <<= 1) { s += __shfl_xor(s, off); ss += __shfl_xor(ss, off); }
  __shared__ float red[8];
  const int wave = tid >> 6, lane = tid & 63;
  if (lane == 0) { red[wave] = s; red[4 + wave] = ss; }
  __syncthreads();
  s  = red[0] + red[1] + red[2] + red[3];
  ss = red[4] + red[5] + red[6] + red[7];
  const float mu   = s * (1.0f / D_MODEL);
  const float var  = ss * (1.0f / D_MODEL) - mu * mu;
  const float rstd = rsqrtf(var + 1e-5f);
  const float4 gv = ((const float4*)g)[tid];
  const float4 bv = ((const float4*)bb)[tid];
  u16x4 o;
  o.x = f2bf((xv.x - mu) * rstd * gv.x + bv.x);
  o.y = f2bf((xv.y - mu) * rstd * gv.y + bv.y);
  o.z = f2bf((xv.z - mu) * rstd * gv.z + bv.z);
  o.w = f2bf((xv.w - mu) * rstd * gv.w + bv.w);
  *(u16x4*)(out + (size_t)row * D_MODEL + tid * 4) = o;
}

// ---------- GEMM: C[M,N] = A[M,K](bf16) * Bt[N,K](bf16)^T, 128x128x32 tiles ----------
// XCD-aware swizzle: dispatch round-robins blocks across 8 XCDs (lin%8). Give each
// XCD a band of 8 M-tile-rows traversed col-major, so co-resident blocks on one XCD
// share 8 A-strips in that XCD's L2 while B streams once per band.
template <bool BIAS, bool RELU, bool RES, bool OBF>
__global__ __launch_bounds__(256) void gemm_bt(const unsigned short* __restrict__ A,
                                               const unsigned short* __restrict__ Bt,
                                               const float* __restrict__ bias,
                                               const float* __restrict__ res,
                                               void* __restrict__ out,
                                               int M, int N, int K) {
  __shared__ __align__(16) unsigned short As[128 * 32];
  __shared__ __align__(16) unsigned short Bs[128 * 32];
  const int tid  = threadIdx.x;
  const int lin = blockIdx.y * gridDim.x + blockIdx.x;   // gridDim.y == 64 always
  const int xcd = lin & 7, idx = lin >> 3;
  const int by = xcd * 8 + (idx & 7);
  const int bx = idx >> 3;
  const int row0 = by * 128, col0 = bx * 128;
  const int wave = tid >> 6, lane = tid & 63;
  const int wm = wave >> 1, wn = wave & 1;
  const int l15 = lane & 15, quad = lane >> 4;
  f32x4 acc[4][4] = {};

  const int fr = tid >> 2, fc = (tid & 3) * 8;
  const unsigned short* gA  = A  + (size_t)(row0 + fr) * K + fc;
  const unsigned short* gA2 = A  + (size_t)(row0 + 64 + fr) * K + fc;
  const unsigned short* gB  = Bt + (size_t)(col0 + fr) * K + fc;
  const unsigned short* gB2 = Bt + (size_t)(col0 + 64 + fr) * K + fc;
  unsigned short* lA  = As + tid * 8;
  unsigned short* lA2 = As + (tid + 256) * 8;
  unsigned short* lB  = Bs + tid * 8;
  unsigned short* lB2 = Bs + (tid + 256) * 8;

  for (int k0 = 0; k0 < K; k0 += 32) {
    gload16(gA + k0, lA);
    gload16(gA2 + k0, lA2);
    gload16(gB + k0, lB);
    gload16(gB2 + k0, lB2);
    __syncthreads();
    bf16x8 af[4], bfr[4];
    #pragma unroll
    for (int t = 0; t < 4; ++t) {
      af[t]  = load8bf(As + (wm * 64 + t * 16 + l15) * 32 + quad * 8);
      bfr[t] = load8bf(Bs + (wn * 64 + t * 16 + l15) * 32 + quad * 8);
    }
    #pragma unroll
    for (int i = 0; i < 4; ++i)
      #pragma unroll
      for (int j = 0; j < 4; ++j)
        acc[i][j] = mfma16(af[i], bfr[j], acc[i][j]);
    __syncthreads();
  }

  const size_t rbase = (size_t)row0 + wm * 64 + quad * 4;
  const int cbase = col0 + wn * 64 + l15;
  #pragma unroll
  for (int i = 0; i < 4; ++i) {
    #pragma unroll
    for (int j = 0; j < 4; ++j) {
      const int col = cbase + j * 16;
      const float bval = BIAS ? bias[col] : 0.0f;
      #pragma unroll
      for (int r = 0; r < 4; ++r) {
        const size_t row = rbase + i * 16 + r;
        float v = acc[i][j][r];
        if (BIAS) v += bval;
        if (RELU) v = fmaxf(v, 0.0f);
        if (RES)  v += res[row * N + col];
        if (OBF)  ((unsigned short*)out)[row * N + col] = f2bf(v);
        else      ((float*)out)[row * N + col] = v;
      }
    }
  }
}

// ---------- K/V pre-pack: kp[bh][t][64], vt[bh][64][t] (V transposed) ----------
__global__ __launch_bounds__(256) void kvpack(const unsigned short* __restrict__ qkv,
                                              unsigned short* __restrict__ kp,
                                              unsigned short* __restrict__ vt) {
  const int t0 = blockIdx.x * 64;
  const int bh = blockIdx.y, b = bh >> 4, h = bh & 15;
  const int tid = threadIdx.x, lane = tid & 63, wave = tid >> 6;
  __shared__ __align__(16) unsigned short vstage[64 * 64];
  const size_t qbase = ((size_t)b * SEQ + t0) * 3072;
  #pragma unroll
  for (int i = 0; i < 2; ++i) {      // K: straight copy, coalesced 16B
    const int cid = i * 256 + tid;
    const int r = cid >> 3, c = cid & 7;
    u32x4 vv = *(const u32x4*)(qkv + qbase + (size_t)r * 3072 + 1024 + h * 64 + c * 8);
    *(u32x4*)(kp + ((size_t)bh * SEQ + t0 + r) * 64 + c * 8) = vv;
  }
  #pragma unroll
  for (int i = 0; i < 2; ++i) {      // V: stage with chunk-XOR swizzle
    const int cid = i * 256 + tid;
    const int r = cid >> 3, p = cid & 7, c = p ^ (r >> 3);
    gload16(qkv + qbase + (size_t)r * 3072 + 2048 + h * 64 + c * 8, vstage + cid * 8);
  }
  __syncthreads();
  #pragma unroll
  for (int it = 0; it < 2; ++it) {   // transpose out: lane holds dim d, 8 tokens
    const int d = (lane & 7) + wave * 8 + it * 32;
    const int tc = lane >> 3;
    unsigned short tmp[8];
    #pragma unroll
    for (int j = 0; j < 8; ++j) {
      const int tj = tc * 8 + j;
      const int p = (d >> 3) ^ tc;
      tmp[j] = vstage[tj * 64 + p * 8 + (d & 7)];
    }
    *(u32x4*)(vt + ((size_t)bh * HDIM + d) * SEQ + t0 + tc * 8) = *(u32x4*)tmp;
  }
}

// ---------- fused causal attention v3 + XCD swizzle ----------
// Fixed-max softmax, triangle pairing (block xb does qblk 15-xb then xb, 34 tiles).
// XCD swizzle: each XCD owns 8 complete (b,h) pairs; its 8 co-resident blocks share
// the K/V stream in that XCD's L2.
__global__ __launch_bounds__(256) void attn3(const unsigned short* __restrict__ qkv,
                                             const unsigned short* __restrict__ kp,
                                             const unsigned short* __restrict__ vt,
                                             unsigned short* __restrict__ attnb) {
  const int lin = (blockIdx.z * 16 + blockIdx.y) * 8 + blockIdx.x;  // 512 blocks
  const int xcd = lin & 7, idx = lin >> 3;                          // idx 0..63
  const int bh = xcd * 8 + (idx >> 3);
  const int xb = idx & 7;
  const int b = bh >> 4, h = bh & 15;
  const int tid = threadIdx.x, wave = tid >> 6, lane = tid & 63;
  const int l15 = lane & 15, quad = lane >> 4;
  const size_t tokbase = (size_t)b * SEQ;

  __shared__ __align__(16) unsigned short ks[64 * 64];       // [key][dim], chunk-swizzled
  __shared__ __align__(16) unsigned short vts[64 * 64];      // [dim][key], chunk-swizzled
  __shared__ __align__(16) unsigned short plds[4][32 * 64];  // per-wave P, swizzled

  const unsigned short* kbase = kp + (size_t)bh * SEQ * HDIM;
  const unsigned short* vbase = vt + (size_t)bh * HDIM * SEQ;
  const float qscale = 0.18033688011112042f;   // 0.125 * log2(e)

  for (int half = 0; half < 2; ++half) {
    const int qblk = (half == 0) ? (15 - xb) : xb;
    const int qw0 = qblk * 128 + wave * 32;

    bf16x8 qf[2][2];
    #pragma unroll
    for (int mf = 0; mf < 2; ++mf)
      #pragma unroll
      for (int kf = 0; kf < 2; ++kf)
        qf[mf][kf] = scale8(load8bf(qkv + (tokbase + qw0 + mf * 16 + l15) * 3072
                                    + h * HDIM + kf * 32 + quad * 8), qscale);

    f32x4 o[2][4] = {};
    float lsum[2][4] = {};

    const int ntiles = qblk * 2 + 2;
    for (int kt = 0; kt < ntiles; ++kt) {
      const int k0 = kt * 64;
      __syncthreads();                       // previous tile fully consumed
      #pragma unroll
      for (int i = 0; i < 2; ++i) {          // stage K tile (8KB)
        const int cid = i * 256 + tid;
        const int r = cid >> 3, p = cid & 7, c = p ^ (r & 7);
        gload16(kbase + (size_t)(k0 + r) * HDIM + c * 8, ks + cid * 8);
      }
      #pragma unroll
      for (int i = 0; i < 2; ++i) {          // stage V^T tile (8KB)
        const int cid = i * 256 + tid;
        const int d = cid >> 3, p = cid & 7, c = p ^ (d & 7);
        gload16(vbase + (size_t)d * SEQ + k0 + c * 8, vts + cid * 8);
      }
      __syncthreads();                       // vmcnt drain -> staged data visible
      if (k0 <= qw0 + 31) {
        // ---- QK^T: 16 MFMAs ----
        f32x4 s[2][4] = {};
        #pragma unroll
        for (int kf = 0; kf < 2; ++kf)
          #pragma unroll
          for (int nf = 0; nf < 4; ++nf) {
            const int row = nf * 16 + l15;
            const int p = (kf * 4 + quad) ^ (row & 7);
            const bf16x8 bk = load8bf(ks + row * 64 + p * 8);
            s[0][nf] = mfma16(qf[0][kf], bk, s[0][nf]);
            s[1][nf] = mfma16(qf[1][kf], bk, s[1][nf]);
          }
        // ---- fixed-max softmax: p = exp2(s), mask, accumulate l, store P ----
        #pragma unroll
        for (int mf = 0; mf < 2; ++mf)
          #pragma unroll
          for (int nf = 0; nf < 4; ++nf) {
            const int key = k0 + nf * 16 + l15;
            #pragma unroll
            for (int r = 0; r < 4; ++r) {
              const int lq = mf * 16 + quad * 4 + r;
              float p = __builtin_amdgcn_exp2f(s[mf][nf][r]);
              p = (key > qw0 + lq) ? 0.0f : p;
              const unsigned int pu = __builtin_bit_cast(unsigned int, p);
              lsum[mf][r] += __builtin_bit_cast(float, pu & 0xFFFF0000u);  // match stored P
              const int pc = ((nf * 16 + l15) >> 3) ^ (lq & 7) ^ ((lq >> 3) & 3);
              plds[wave][lq * 64 + pc * 8 + (l15 & 7)] = (unsigned short)(pu >> 16);
            }
          }
        __builtin_amdgcn_s_waitcnt(0);       // wave-local plds writes -> reads
        // ---- PV: 16 MFMAs ----
        #pragma unroll
        for (int kf = 0; kf < 2; ++kf) {
          bf16x8 pa[2];
          #pragma unroll
          for (int mf = 0; mf < 2; ++mf) {
            const int lq = mf * 16 + l15;
            const int p = (kf * 4 + quad) ^ (lq & 7) ^ ((lq >> 3) & 3);
            pa[mf] = load8bf(&plds[wave][lq * 64 + p * 8]);
          }
          #pragma unroll
          for (int df = 0; df < 4; ++df) {
            const int row = df * 16 + l15;
            const int p = (kf * 4 + quad) ^ (row & 7);
            const bf16x8 vb = load8bf(vts + row * 64 + p * 8);
            o[0][df] = mfma16(pa[0], vb, o[0][df]);
            o[1][df] = mfma16(pa[1], vb, o[1][df]);
          }
        }
      }
    }
    // ---- normalize + write (one butterfly per row, once per half) ----
    #pragma unroll
    for (int mf = 0; mf < 2; ++mf)
      #pragma unroll
      for (int r = 0; r < 4; ++r) {
        float l = lsum[mf][r];
        #pragma unroll
        for (int off = 1; off < 16; off <<= 1) l += __shfl_xor(l, off);
        const float rl = 1.0f / l;
        const size_t row = tokbase + qw0 + mf * 16 + quad * 4 + r;
        #pragma unroll
        for (int df = 0; df < 4; ++df)
          attnb[row * D_MODEL + h * HDIM + df * 16 + l15] = f2bf(o[mf][df][r] * rl);
      }
  }
}

// ---------- host ----------
extern "C" void kernel_launch(void* const* d_in, const int* in_sizes, int n_in,
                              void* d_out, int out_size, void* d_ws, size_t ws_size,
                              hipStream_t stream) {
  const float* x    = (const float*)d_in[0];
  const float* wq   = (const float*)d_in[1];
  const float* wk   = (const float*)d_in[2];
  const float* wv   = (const float*)d_in[3];
  const float* wo   = (const float*)d_in[4];
  const float* bo   = (const float*)d_in[5];
  const float* w1   = (const float*)d_in[6];
  const float* b1   = (const float*)d_in[7];
  const float* w2   = (const float*)d_in[8];
  const float* b2   = (const float*)d_in[9];
  const float* g1   = (const float*)d_in[10];
  const float* bl1  = (const float*)d_in[11];
  const float* g2   = (const float*)d_in[12];
  const float* bl2  = (const float*)d_in[13];
  float* out = (float*)d_out;

  char* ws = (char*)d_ws;
  size_t off = 0;
  auto alloc = [&](size_t bytes) { char* p = ws + off; off += (bytes + 255) & ~(size_t)255; return p; };
  unsigned short* wqkv_t = (unsigned short*)alloc((size_t)3072 * 1024 * 2);
  unsigned short* wo_t   = (unsigned short*)alloc((size_t)1024 * 1024 * 2);
  unsigned short* w1_t   = (unsigned short*)alloc((size_t)4096 * 1024 * 2);
  unsigned short* w2_t   = (unsigned short*)alloc((size_t)1024 * 4096 * 2);
  unsigned short* h1     = (unsigned short*)alloc((size_t)NTOK * 1024 * 2);
  unsigned short* qkv    = (unsigned short*)alloc((size_t)NTOK * 3072 * 2);
  unsigned short* attnb  = (unsigned short*)alloc((size_t)NTOK * 1024 * 2);
  unsigned short* h2     = (unsigned short*)alloc((size_t)NTOK * 1024 * 2);
  unsigned short* ffn1   = (unsigned short*)alloc((size_t)NTOK * 4096 * 2);
  unsigned short* kpb = h1;   // alias: dead after QKV GEMM
  unsigned short* vtb = h2;   // alias: ln2 writes h2 after attention completes

  // weights -> bf16 [N][K] via LDS-tiled transpose (coalesced both sides)
  tcastT<<<dim3(32, 32), 256, 0, stream>>>(wq, wqkv_t,               1024, 1024);
  tcastT<<<dim3(32, 32), 256, 0, stream>>>(wk, wqkv_t + 1024 * 1024, 1024, 1024);
  tcastT<<<dim3(32, 32), 256, 0, stream>>>(wv, wqkv_t + 2048 * 1024, 1024, 1024);
  tcastT<<<dim3(32, 32), 256, 0, stream>>>(wo, wo_t,                 1024, 1024);
  tcastT<<<dim3(128, 32), 256, 0, stream>>>(w1, w1_t, 1024, 4096);
  tcastT<<<dim3(32, 128), 256, 0, stream>>>(w2, w2_t, 4096, 1024);

  ln_kernel<<<NTOK, 256, 0, stream>>>(x, g1, bl1, h1);
  gemm_bt<false, false, false, true><<<dim3(24, 64), 256, 0, stream>>>(
      h1, wqkv_t, nullptr, nullptr, qkv, NTOK, 3072, 1024);
  kvpack<<<dim3(SEQ / 64, NBATCH * NHEAD), 256, 0, stream>>>(qkv, kpb, vtb);
  attn3<<<dim3(SEQ / 256, NHEAD, NBATCH), 256, 0, stream>>>(qkv, kpb, vtb, attnb);
  gemm_bt<true, false, true, false><<<dim3(8, 64), 256, 0, stream>>>(
      attnb, wo_t, bo, x, out, NTOK, 1024, 1024);
  ln_kernel<<<NTOK, 256, 0, stream>>>(out, g2, bl2, h2);
  gemm_bt<true, true, false, true><<<dim3(32, 64), 256, 0, stream>>>(
      h2, w1_t, b1, nullptr, ffn1, NTOK, 4096, 1024);
  gemm_bt<true, false, true, false><<<dim3(8, 64), 256, 0, stream>>>(
      ffn1, w2_t, b2, out, out, NTOK, 1024, 4096);
  (void)in_sizes; (void)n_in; (void)out_size; (void)ws_size;
}

// Round 5
// 515.271 us; speedup vs baseline: 1.8399x; 1.0433x over previous
//
#include <hip/hip_runtime.h>
#include <cstdint>

// ---------- types ----------
typedef __bf16 bf16x8 __attribute__((ext_vector_type(8)));
typedef float f32x4 __attribute__((ext_vector_type(4)));
typedef unsigned int u32x4 __attribute__((ext_vector_type(4)));
typedef unsigned short u16x4 __attribute__((ext_vector_type(4)));

#define D_MODEL 1024
#define SEQ     2048
#define NBATCH  4
#define NHEAD   16
#define HDIM    64
#define NTOK    (NBATCH * SEQ)   // 8192

__device__ __forceinline__ unsigned short f2bf(float f) {
  unsigned int u = __builtin_bit_cast(unsigned int, f);
  u += 0x7FFFu + ((u >> 16) & 1u);           // round-to-nearest-even
  return (unsigned short)(u >> 16);
}

__device__ __forceinline__ bf16x8 load8bf(const unsigned short* p) {
  return __builtin_bit_cast(bf16x8, *(const u32x4*)p);
}

__device__ __forceinline__ f32x4 mfma16(bf16x8 a, bf16x8 b, f32x4 c) {
  return __builtin_amdgcn_mfma_f32_16x16x32_bf16(a, b, c, 0, 0, 0);
}

// async global->LDS, 16B per lane; LDS dest must be waveBase + lane*16
__device__ __forceinline__ void gload16(const unsigned short* g, unsigned short* l) {
  __builtin_amdgcn_global_load_lds((__attribute__((address_space(1))) void*)g,
                                   (__attribute__((address_space(3))) void*)l, 16, 0, 0);
}

// scale a bf16x8 fragment by s (round-to-nearest), used once per kernel for Q
__device__ __forceinline__ bf16x8 scale8(bf16x8 v, float s) {
  u32x4 u = __builtin_bit_cast(u32x4, v);
  unsigned short out[8];
  #pragma unroll
  for (int i = 0; i < 4; ++i) {
    unsigned int w = u[i];
    float lo = __builtin_bit_cast(float, w << 16) * s;
    float hi = __builtin_bit_cast(float, w & 0xFFFF0000u) * s;
    out[2 * i]     = f2bf(lo);
    out[2 * i + 1] = f2bf(hi);
  }
  return __builtin_bit_cast(bf16x8, *(u32x4*)out);
}

// ---------- transposing weight cast: out[n][k] = bf16(in[k][n]), LDS-tiled ----------
__global__ __launch_bounds__(256) void tcastT(const float* __restrict__ in,
                                              unsigned short* __restrict__ out,
                                              int K, int N) {
  __shared__ float tile[32][33];
  const int k0 = blockIdx.y * 32, n0 = blockIdx.x * 32;
  const int tx = threadIdx.x & 31, ty = threadIdx.x >> 5;   // ty 0..7
  #pragma unroll
  for (int j = 0; j < 4; ++j)
    tile[ty + 8 * j][tx] = in[(size_t)(k0 + ty + 8 * j) * N + n0 + tx];
  __syncthreads();
  #pragma unroll
  for (int j = 0; j < 4; ++j)
    out[(size_t)(n0 + ty + 8 * j) * K + k0 + tx] = f2bf(tile[tx][ty + 8 * j]);
}

// ---------- layernorm (D=1024), fp32 in -> bf16 out ----------
__global__ __launch_bounds__(256) void ln_kernel(const float* __restrict__ x,
                                                 const float* __restrict__ g,
                                                 const float* __restrict__ bb,
                                                 unsigned short* __restrict__ out) {
  const int row = blockIdx.x, tid = threadIdx.x;
  const float4 xv = ((const float4*)(x + (size_t)row * D_MODEL))[tid];
  float s  = xv.x + xv.y + xv.z + xv.w;
  float ss = xv.x * xv.x + xv.y * xv.y + xv.z * xv.z + xv.w * xv.w;
  #pragma unroll
  for (int off = 1; off < 64; off <<= 1) { s += __shfl_xor(s, off); ss += __shfl_xor(ss, off); }
  __shared__ float red[8];
  const int wave = tid >> 6, lane = tid & 63;
  if (lane == 0) { red[wave] = s; red[4 + wave] = ss; }
  __syncthreads();
  s  = red[0] + red[1] + red[2] + red[3];
  ss = red[4] + red[5] + red[6] + red[7];
  const float mu   = s * (1.0f / D_MODEL);
  const float var  = ss * (1.0f / D_MODEL) - mu * mu;
  const float rstd = rsqrtf(var + 1e-5f);
  const float4 gv = ((const float4*)g)[tid];
  const float4 bv = ((const float4*)bb)[tid];
  u16x4 o;
  o.x = f2bf((xv.x - mu) * rstd * gv.x + bv.x);
  o.y = f2bf((xv.y - mu) * rstd * gv.y + bv.y);
  o.z = f2bf((xv.z - mu) * rstd * gv.z + bv.z);
  o.w = f2bf((xv.w - mu) * rstd * gv.w + bv.w);
  *(u16x4*)(out + (size_t)row * D_MODEL + tid * 4) = o;
}

// ---------- GEMM: C[M,N] = A[M,K](bf16) * Bt[N,K](bf16)^T ----------
// 128x128 tile, BK=64 (32 MFMAs per barrier drain vs 16 at BK=32), 32KB LDS.
// Chunk-XOR swizzle: row = 128B = one bank wrap; global chunk c of row r is
// stored at position c^(r&7) (swizzle applied on the global SOURCE address since
// global_load_lds dest is pinned to lane order). Fragment reads XOR the same
// pattern -> uniform 8 words/bank (the b128 floor, no serialization).
// XCD swizzle: lin%8 = XCD; band of 8 M-rows traversed col-major for L2 reuse.
template <bool BIAS, bool RELU, bool RES, bool OBF>
__global__ __launch_bounds__(256) void gemm_bt(const unsigned short* __restrict__ A,
                                               const unsigned short* __restrict__ Bt,
                                               const float* __restrict__ bias,
                                               const float* __restrict__ res,
                                               void* __restrict__ out,
                                               int M, int N, int K) {
  __shared__ __align__(16) unsigned short As[128 * 64];
  __shared__ __align__(16) unsigned short Bs[128 * 64];
  const int tid  = threadIdx.x;
  const int lin = blockIdx.y * gridDim.x + blockIdx.x;   // gridDim.y == 64 always
  const int xcd = lin & 7, idx = lin >> 3;
  const int by = xcd * 8 + (idx & 7);
  const int bx = idx >> 3;
  const int row0 = by * 128, col0 = bx * 128;
  const int wave = tid >> 6, lane = tid & 63;
  const int wm = wave >> 1, wn = wave & 1;
  const int l15 = lane & 15, quad = lane >> 4;
  f32x4 acc[4][4] = {};

  // staging: 1024 chunks of 16B per tile, 4 per thread (i=0..3), row = i*32 + tr.
  const int tr = tid >> 3;                        // base row 0..31
  const int tc = (tid & 7) ^ (tr & 7);            // swizzled source chunk
  const unsigned short* gA = A  + (size_t)(row0 + tr) * K + tc * 8;
  const unsigned short* gB = Bt + (size_t)(col0 + tr) * K + tc * 8;

  // fragment read offsets: row = (w*64 + t*16 + l15), pos = (kf*4+quad)^(l15&7)
  const int rowA = (wm * 64 + l15) * 64;
  const int rowB = (wn * 64 + l15) * 64;
  const int swz0 = (quad ^ (l15 & 7)) * 8;
  const int swz1 = ((4 + quad) ^ (l15 & 7)) * 8;

  for (int k0 = 0; k0 < K; k0 += 64) {
    #pragma unroll
    for (int i = 0; i < 4; ++i) {
      gload16(gA + (size_t)(i * 32) * K + k0, As + (i * 256 + tid) * 8);
      gload16(gB + (size_t)(i * 32) * K + k0, Bs + (i * 256 + tid) * 8);
    }
    __syncthreads();   // vmcnt drain -> staged data visible
    #pragma unroll
    for (int kf = 0; kf < 2; ++kf) {
      const int swz = kf ? swz1 : swz0;
      bf16x8 af[4], bfr[4];
      #pragma unroll
      for (int t = 0; t < 4; ++t) {
        af[t]  = load8bf(As + rowA + t * 1024 + swz);
        bfr[t] = load8bf(Bs + rowB + t * 1024 + swz);
      }
      #pragma unroll
      for (int i = 0; i < 4; ++i)
        #pragma unroll
        for (int j = 0; j < 4; ++j)
          acc[i][j] = mfma16(af[i], bfr[j], acc[i][j]);
    }
    __syncthreads();   // all reads done before next stage overwrites
  }

  const size_t rbase = (size_t)row0 + wm * 64 + quad * 4;
  const int cbase = col0 + wn * 64 + l15;
  #pragma unroll
  for (int i = 0; i < 4; ++i) {
    #pragma unroll
    for (int j = 0; j < 4; ++j) {
      const int col = cbase + j * 16;
      const float bval = BIAS ? bias[col] : 0.0f;
      #pragma unroll
      for (int r = 0; r < 4; ++r) {
        const size_t row = rbase + i * 16 + r;
        float v = acc[i][j][r];
        if (BIAS) v += bval;
        if (RELU) v = fmaxf(v, 0.0f);
        if (RES)  v += res[row * N + col];
        if (OBF)  ((unsigned short*)out)[row * N + col] = f2bf(v);
        else      ((float*)out)[row * N + col] = v;
      }
    }
  }
}

// ---------- K/V pre-pack: kp[bh][t][64], vt[bh][64][t] (V transposed) ----------
__global__ __launch_bounds__(256) void kvpack(const unsigned short* __restrict__ qkv,
                                              unsigned short* __restrict__ kp,
                                              unsigned short* __restrict__ vt) {
  const int t0 = blockIdx.x * 64;
  const int bh = blockIdx.y, b = bh >> 4, h = bh & 15;
  const int tid = threadIdx.x, lane = tid & 63, wave = tid >> 6;
  __shared__ __align__(16) unsigned short vstage[64 * 64];
  const size_t qbase = ((size_t)b * SEQ + t0) * 3072;
  #pragma unroll
  for (int i = 0; i < 2; ++i) {      // K: straight copy, coalesced 16B
    const int cid = i * 256 + tid;
    const int r = cid >> 3, c = cid & 7;
    u32x4 vv = *(const u32x4*)(qkv + qbase + (size_t)r * 3072 + 1024 + h * 64 + c * 8);
    *(u32x4*)(kp + ((size_t)bh * SEQ + t0 + r) * 64 + c * 8) = vv;
  }
  #pragma unroll
  for (int i = 0; i < 2; ++i) {      // V: stage with chunk-XOR swizzle
    const int cid = i * 256 + tid;
    const int r = cid >> 3, p = cid & 7, c = p ^ (r >> 3);
    gload16(qkv + qbase + (size_t)r * 3072 + 2048 + h * 64 + c * 8, vstage + cid * 8);
  }
  __syncthreads();
  #pragma unroll
  for (int it = 0; it < 2; ++it) {   // transpose out: lane holds dim d, 8 tokens
    const int d = (lane & 7) + wave * 8 + it * 32;
    const int tc = lane >> 3;
    unsigned short tmp[8];
    #pragma unroll
    for (int j = 0; j < 8; ++j) {
      const int tj = tc * 8 + j;
      const int p = (d >> 3) ^ tc;
      tmp[j] = vstage[tj * 64 + p * 8 + (d & 7)];
    }
    *(u32x4*)(vt + ((size_t)bh * HDIM + d) * SEQ + t0 + tc * 8) = *(u32x4*)tmp;
  }
}

// ---------- fused causal attention v3 + XCD swizzle ----------
__global__ __launch_bounds__(256) void attn3(const unsigned short* __restrict__ qkv,
                                             const unsigned short* __restrict__ kp,
                                             const unsigned short* __restrict__ vt,
                                             unsigned short* __restrict__ attnb) {
  const int lin = (blockIdx.z * 16 + blockIdx.y) * 8 + blockIdx.x;  // 512 blocks
  const int xcd = lin & 7, idx = lin >> 3;                          // idx 0..63
  const int bh = xcd * 8 + (idx >> 3);
  const int xb = idx & 7;
  const int b = bh >> 4, h = bh & 15;
  const int tid = threadIdx.x, wave = tid >> 6, lane = tid & 63;
  const int l15 = lane & 15, quad = lane >> 4;
  const size_t tokbase = (size_t)b * SEQ;

  __shared__ __align__(16) unsigned short ks[64 * 64];       // [key][dim], chunk-swizzled
  __shared__ __align__(16) unsigned short vts[64 * 64];      // [dim][key], chunk-swizzled
  __shared__ __align__(16) unsigned short plds[4][32 * 64];  // per-wave P, swizzled

  const unsigned short* kbase = kp + (size_t)bh * SEQ * HDIM;
  const unsigned short* vbase = vt + (size_t)bh * HDIM * SEQ;
  const float qscale = 0.18033688011112042f;   // 0.125 * log2(e)

  for (int half = 0; half < 2; ++half) {
    const int qblk = (half == 0) ? (15 - xb) : xb;
    const int qw0 = qblk * 128 + wave * 32;

    bf16x8 qf[2][2];
    #pragma unroll
    for (int mf = 0; mf < 2; ++mf)
      #pragma unroll
      for (int kf = 0; kf < 2; ++kf)
        qf[mf][kf] = scale8(load8bf(qkv + (tokbase + qw0 + mf * 16 + l15) * 3072
                                    + h * HDIM + kf * 32 + quad * 8), qscale);

    f32x4 o[2][4] = {};
    float lsum[2][4] = {};

    const int ntiles = qblk * 2 + 2;
    for (int kt = 0; kt < ntiles; ++kt) {
      const int k0 = kt * 64;
      __syncthreads();                       // previous tile fully consumed
      #pragma unroll
      for (int i = 0; i < 2; ++i) {          // stage K tile (8KB)
        const int cid = i * 256 + tid;
        const int r = cid >> 3, p = cid & 7, c = p ^ (r & 7);
        gload16(kbase + (size_t)(k0 + r) * HDIM + c * 8, ks + cid * 8);
      }
      #pragma unroll
      for (int i = 0; i < 2; ++i) {          // stage V^T tile (8KB)
        const int cid = i * 256 + tid;
        const int d = cid >> 3, p = cid & 7, c = p ^ (d & 7);
        gload16(vbase + (size_t)d * SEQ + k0 + c * 8, vts + cid * 8);
      }
      __syncthreads();                       // vmcnt drain -> staged data visible
      if (k0 <= qw0 + 31) {
        // ---- QK^T: 16 MFMAs ----
        f32x4 s[2][4] = {};
        #pragma unroll
        for (int kf = 0; kf < 2; ++kf)
          #pragma unroll
          for (int nf = 0; nf < 4; ++nf) {
            const int row = nf * 16 + l15;
            const int p = (kf * 4 + quad) ^ (row & 7);
            const bf16x8 bk = load8bf(ks + row * 64 + p * 8);
            s[0][nf] = mfma16(qf[0][kf], bk, s[0][nf]);
            s[1][nf] = mfma16(qf[1][kf], bk, s[1][nf]);
          }
        // ---- fixed-max softmax: p = exp2(s), mask, accumulate l, store P ----
        #pragma unroll
        for (int mf = 0; mf < 2; ++mf)
          #pragma unroll
          for (int nf = 0; nf < 4; ++nf) {
            const int key = k0 + nf * 16 + l15;
            #pragma unroll
            for (int r = 0; r < 4; ++r) {
              const int lq = mf * 16 + quad * 4 + r;
              float p = __builtin_amdgcn_exp2f(s[mf][nf][r]);
              p = (key > qw0 + lq) ? 0.0f : p;
              const unsigned int pu = __builtin_bit_cast(unsigned int, p);
              lsum[mf][r] += __builtin_bit_cast(float, pu & 0xFFFF0000u);  // match stored P
              const int pc = ((nf * 16 + l15) >> 3) ^ (lq & 7) ^ ((lq >> 3) & 3);
              plds[wave][lq * 64 + pc * 8 + (l15 & 7)] = (unsigned short)(pu >> 16);
            }
          }
        __builtin_amdgcn_s_waitcnt(0);       // wave-local plds writes -> reads
        // ---- PV: 16 MFMAs ----
        #pragma unroll
        for (int kf = 0; kf < 2; ++kf) {
          bf16x8 pa[2];
          #pragma unroll
          for (int mf = 0; mf < 2; ++mf) {
            const int lq = mf * 16 + l15;
            const int p = (kf * 4 + quad) ^ (lq & 7) ^ ((lq >> 3) & 3);
            pa[mf] = load8bf(&plds[wave][lq * 64 + p * 8]);
          }
          #pragma unroll
          for (int df = 0; df < 4; ++df) {
            const int row = df * 16 + l15;
            const int p = (kf * 4 + quad) ^ (row & 7);
            const bf16x8 vb = load8bf(vts + row * 64 + p * 8);
            o[0][df] = mfma16(pa[0], vb, o[0][df]);
            o[1][df] = mfma16(pa[1], vb, o[1][df]);
          }
        }
      }
    }
    // ---- normalize + write (one butterfly per row, once per half) ----
    #pragma unroll
    for (int mf = 0; mf < 2; ++mf)
      #pragma unroll
      for (int r = 0; r < 4; ++r) {
        float l = lsum[mf][r];
        #pragma unroll
        for (int off = 1; off < 16; off <<= 1) l += __shfl_xor(l, off);
        const float rl = 1.0f / l;
        const size_t row = tokbase + qw0 + mf * 16 + quad * 4 + r;
        #pragma unroll
        for (int df = 0; df < 4; ++df)
          attnb[row * D_MODEL + h * HDIM + df * 16 + l15] = f2bf(o[mf][df][r] * rl);
      }
  }
}

// ---------- host ----------
extern "C" void kernel_launch(void* const* d_in, const int* in_sizes, int n_in,
                              void* d_out, int out_size, void* d_ws, size_t ws_size,
                              hipStream_t stream) {
  const float* x    = (const float*)d_in[0];
  const float* wq   = (const float*)d_in[1];
  const float* wk   = (const float*)d_in[2];
  const float* wv   = (const float*)d_in[3];
  const float* wo   = (const float*)d_in[4];
  const float* bo   = (const float*)d_in[5];
  const float* w1   = (const float*)d_in[6];
  const float* b1   = (const float*)d_in[7];
  const float* w2   = (const float*)d_in[8];
  const float* b2   = (const float*)d_in[9];
  const float* g1   = (const float*)d_in[10];
  const float* bl1  = (const float*)d_in[11];
  const float* g2   = (const float*)d_in[12];
  const float* bl2  = (const float*)d_in[13];
  float* out = (float*)d_out;

  char* ws = (char*)d_ws;
  size_t off = 0;
  auto alloc = [&](size_t bytes) { char* p = ws + off; off += (bytes + 255) & ~(size_t)255; return p; };
  unsigned short* wqkv_t = (unsigned short*)alloc((size_t)3072 * 1024 * 2);
  unsigned short* wo_t   = (unsigned short*)alloc((size_t)1024 * 1024 * 2);
  unsigned short* w1_t   = (unsigned short*)alloc((size_t)4096 * 1024 * 2);
  unsigned short* w2_t   = (unsigned short*)alloc((size_t)1024 * 4096 * 2);
  unsigned short* h1     = (unsigned short*)alloc((size_t)NTOK * 1024 * 2);
  unsigned short* qkv    = (unsigned short*)alloc((size_t)NTOK * 3072 * 2);
  unsigned short* attnb  = (unsigned short*)alloc((size_t)NTOK * 1024 * 2);
  unsigned short* h2     = (unsigned short*)alloc((size_t)NTOK * 1024 * 2);
  unsigned short* ffn1   = (unsigned short*)alloc((size_t)NTOK * 4096 * 2);
  unsigned short* kpb = h1;   // alias: dead after QKV GEMM
  unsigned short* vtb = h2;   // alias: ln2 writes h2 after attention completes

  // weights -> bf16 [N][K] via LDS-tiled transpose (coalesced both sides)
  tcastT<<<dim3(32, 32), 256, 0, stream>>>(wq, wqkv_t,               1024, 1024);
  tcastT<<<dim3(32, 32), 256, 0, stream>>>(wk, wqkv_t + 1024 * 1024, 1024, 1024);
  tcastT<<<dim3(32, 32), 256, 0, stream>>>(wv, wqkv_t + 2048 * 1024, 1024, 1024);
  tcastT<<<dim3(32, 32), 256, 0, stream>>>(wo, wo_t,                 1024, 1024);
  tcastT<<<dim3(128, 32), 256, 0, stream>>>(w1, w1_t, 1024, 4096);
  tcastT<<<dim3(32, 128), 256, 0, stream>>>(w2, w2_t, 4096, 1024);

  ln_kernel<<<NTOK, 256, 0, stream>>>(x, g1, bl1, h1);
  gemm_bt<false, false, false, true><<<dim3(24, 64), 256, 0, stream>>>(
      h1, wqkv_t, nullptr, nullptr, qkv, NTOK, 3072, 1024);
  kvpack<<<dim3(SEQ / 64, NBATCH * NHEAD), 256, 0, stream>>>(qkv, kpb, vtb);
  attn3<<<dim3(SEQ / 256, NHEAD, NBATCH), 256, 0, stream>>>(qkv, kpb, vtb, attnb);
  gemm_bt<true, false, true, false><<<dim3(8, 64), 256, 0, stream>>>(
      attnb, wo_t, bo, x, out, NTOK, 1024, 1024);
  ln_kernel<<<NTOK, 256, 0, stream>>>(out, g2, bl2, h2);
  gemm_bt<true, true, false, true><<<dim3(32, 64), 256, 0, stream>>>(
      h2, w1_t, b1, nullptr, ffn1, NTOK, 4096, 1024);
  gemm_bt<true, false, true, false><<<dim3(8, 64), 256, 0, stream>>>(
      ffn1, w2_t, b2, out, out, NTOK, 1024, 4096);
  (void)in_sizes; (void)n_in; (void)out_size; (void)ws_size;
}

// Round 6
// 479.387 us; speedup vs baseline: 1.9777x; 1.0749x over previous
//
#include <hip/hip_runtime.h>
#include <cstdint>

// ---------- types ----------
typedef __bf16 bf16x8 __attribute__((ext_vector_type(8)));
typedef float f32x4 __attribute__((ext_vector_type(4)));
typedef unsigned int u32x4 __attribute__((ext_vector_type(4)));
typedef unsigned short u16x4 __attribute__((ext_vector_type(4)));

#define D_MODEL 1024
#define SEQ     2048
#define NBATCH  4
#define NHEAD   16
#define HDIM    64
#define NTOK    (NBATCH * SEQ)   // 8192
#define QSCALE  0.18033688011112042f   // 0.125 * log2(e)

__device__ __forceinline__ unsigned short f2bf(float f) {
  unsigned int u = __builtin_bit_cast(unsigned int, f);
  u += 0x7FFFu + ((u >> 16) & 1u);           // round-to-nearest-even
  return (unsigned short)(u >> 16);
}

__device__ __forceinline__ bf16x8 load8bf(const unsigned short* p) {
  return __builtin_bit_cast(bf16x8, *(const u32x4*)p);
}

__device__ __forceinline__ f32x4 mfma16(bf16x8 a, bf16x8 b, f32x4 c) {
  return __builtin_amdgcn_mfma_f32_16x16x32_bf16(a, b, c, 0, 0, 0);
}

// async global->LDS, 16B per lane; LDS dest must be waveBase + lane*16
__device__ __forceinline__ void gload16(const unsigned short* g, unsigned short* l) {
  __builtin_amdgcn_global_load_lds((__attribute__((address_space(1))) void*)g,
                                   (__attribute__((address_space(3))) void*)l, 16, 0, 0);
}

// ---------- batched transposing weight cast: out[n][k] = bf16(in[k][n]) ----------
// one launch for all 6 weights; 12288 tiles of 32x32.
__global__ __launch_bounds__(256) void tcast_all(const float* __restrict__ wq,
                                                 const float* __restrict__ wk,
                                                 const float* __restrict__ wv,
                                                 const float* __restrict__ wo,
                                                 const float* __restrict__ w1,
                                                 const float* __restrict__ w2,
                                                 unsigned short* __restrict__ wqkv_t,
                                                 unsigned short* __restrict__ wo_t,
                                                 unsigned short* __restrict__ w1_t,
                                                 unsigned short* __restrict__ w2_t) {
  const int id = blockIdx.x;
  const float* in; unsigned short* out; int K, N, k0, n0;
  if (id < 4096) {             // wq/wk/wv/wo: 1024x1024 each, 1024 tiles each
    const int seg = id >> 10, r = id & 1023;
    in  = seg == 0 ? wq : seg == 1 ? wk : seg == 2 ? wv : wo;
    out = seg == 3 ? wo_t : wqkv_t + (size_t)seg * 1024 * 1024;
    K = 1024; N = 1024; n0 = (r & 31) * 32; k0 = (r >> 5) * 32;
  } else if (id < 8192) {      // w1: K=1024 -> N=4096
    const int r = id - 4096;
    in = w1; out = w1_t; K = 1024; N = 4096;
    n0 = (r & 127) * 32; k0 = (r >> 7) * 32;
  } else {                     // w2: K=4096 -> N=1024
    const int r = id - 8192;
    in = w2; out = w2_t; K = 4096; N = 1024;
    n0 = (r & 31) * 32; k0 = (r >> 5) * 32;
  }
  __shared__ float tile[32][33];
  const int tx = threadIdx.x & 31, ty = threadIdx.x >> 5;   // ty 0..7
  #pragma unroll
  for (int j = 0; j < 4; ++j)
    tile[ty + 8 * j][tx] = in[(size_t)(k0 + ty + 8 * j) * N + n0 + tx];
  __syncthreads();
  #pragma unroll
  for (int j = 0; j < 4; ++j)
    out[(size_t)(n0 + ty + 8 * j) * K + k0 + tx] = f2bf(tile[tx][ty + 8 * j]);
}

// ---------- layernorm (D=1024), fp32 in -> bf16 out ----------
__global__ __launch_bounds__(256) void ln_kernel(const float* __restrict__ x,
                                                 const float* __restrict__ g,
                                                 const float* __restrict__ bb,
                                                 unsigned short* __restrict__ out) {
  const int row = blockIdx.x, tid = threadIdx.x;
  const float4 xv = ((const float4*)(x + (size_t)row * D_MODEL))[tid];
  float s  = xv.x + xv.y + xv.z + xv.w;
  float ss = xv.x * xv.x + xv.y * xv.y + xv.z * xv.z + xv.w * xv.w;
  #pragma unroll
  for (int off = 1; off < 64; off <<= 1) { s += __shfl_xor(s, off); ss += __shfl_xor(ss, off); }
  __shared__ float red[8];
  const int wave = tid >> 6, lane = tid & 63;
  if (lane == 0) { red[wave] = s; red[4 + wave] = ss; }
  __syncthreads();
  s  = red[0] + red[1] + red[2] + red[3];
  ss = red[4] + red[5] + red[6] + red[7];
  const float mu   = s * (1.0f / D_MODEL);
  const float var  = ss * (1.0f / D_MODEL) - mu * mu;
  const float rstd = rsqrtf(var + 1e-5f);
  const float4 gv = ((const float4*)g)[tid];
  const float4 bv = ((const float4*)bb)[tid];
  u16x4 o;
  o.x = f2bf((xv.x - mu) * rstd * gv.x + bv.x);
  o.y = f2bf((xv.y - mu) * rstd * gv.y + bv.y);
  o.z = f2bf((xv.z - mu) * rstd * gv.z + bv.z);
  o.w = f2bf((xv.w - mu) * rstd * gv.w + bv.w);
  *(u16x4*)(out + (size_t)row * D_MODEL + tid * 4) = o;
}

// ---------- GEMM: C[M,N] = A[M,K](bf16) * Bt[N,K](bf16)^T ----------
// 128x128 tile, BK=64, chunk-XOR swizzled LDS (0 bank conflicts), XCD-banded
// block order. QKV=true: epilogue scatters into attention-ready layouts:
//   cols 0..1023  -> qb[t][1024]   pre-scaled by QSCALE
//   cols 1024..   -> kp[bh][t][64]
//   cols 2048..   -> vt[bh][d][2048]   (transposed; 4 consecutive t per store)
template <bool BIAS, bool RELU, bool RES, bool OBF, bool QKV>
__global__ __launch_bounds__(256) void gemm_bt(const unsigned short* __restrict__ A,
                                               const unsigned short* __restrict__ Bt,
                                               const float* __restrict__ bias,
                                               const float* __restrict__ res,
                                               void* __restrict__ out,
                                               unsigned short* __restrict__ qb,
                                               unsigned short* __restrict__ kp,
                                               unsigned short* __restrict__ vt,
                                               int M, int N, int K) {
  __shared__ __align__(16) unsigned short As[128 * 64];
  __shared__ __align__(16) unsigned short Bs[128 * 64];
  const int tid  = threadIdx.x;
  const int lin = blockIdx.y * gridDim.x + blockIdx.x;   // gridDim.y == 64 always
  const int xcd = lin & 7, idx = lin >> 3;
  const int by = xcd * 8 + (idx & 7);
  const int bx = idx >> 3;
  const int row0 = by * 128, col0 = bx * 128;
  const int wave = tid >> 6, lane = tid & 63;
  const int wm = wave >> 1, wn = wave & 1;
  const int l15 = lane & 15, quad = lane >> 4;
  f32x4 acc[4][4] = {};

  // staging: 1024 chunks of 16B per tile, 4 per thread (i=0..3), row = i*32 + tr.
  const int tr = tid >> 3;                        // base row 0..31
  const int tc = (tid & 7) ^ (tr & 7);            // swizzled source chunk
  const unsigned short* gA = A  + (size_t)(row0 + tr) * K + tc * 8;
  const unsigned short* gB = Bt + (size_t)(col0 + tr) * K + tc * 8;

  const int rowA = (wm * 64 + l15) * 64;
  const int rowB = (wn * 64 + l15) * 64;
  const int swz0 = (quad ^ (l15 & 7)) * 8;
  const int swz1 = ((4 + quad) ^ (l15 & 7)) * 8;

  for (int k0 = 0; k0 < K; k0 += 64) {
    #pragma unroll
    for (int i = 0; i < 4; ++i) {
      gload16(gA + (size_t)(i * 32) * K + k0, As + (i * 256 + tid) * 8);
      gload16(gB + (size_t)(i * 32) * K + k0, Bs + (i * 256 + tid) * 8);
    }
    __syncthreads();   // vmcnt drain -> staged data visible
    #pragma unroll
    for (int kf = 0; kf < 2; ++kf) {
      const int swz = kf ? swz1 : swz0;
      bf16x8 af[4], bfr[4];
      #pragma unroll
      for (int t = 0; t < 4; ++t) {
        af[t]  = load8bf(As + rowA + t * 1024 + swz);
        bfr[t] = load8bf(Bs + rowB + t * 1024 + swz);
      }
      #pragma unroll
      for (int i = 0; i < 4; ++i)
        #pragma unroll
        for (int j = 0; j < 4; ++j)
          acc[i][j] = mfma16(af[i], bfr[j], acc[i][j]);
    }
    __syncthreads();   // all reads done before next stage overwrites
  }

  const size_t rbase = (size_t)row0 + wm * 64 + quad * 4;
  const int cbase = col0 + wn * 64 + l15;
  if (QKV) {
    const int sec = col0 >> 10;           // block-uniform: 0=Q, 1=K, 2=V
    #pragma unroll
    for (int i = 0; i < 4; ++i) {
      #pragma unroll
      for (int j = 0; j < 4; ++j) {
        const int col = cbase + j * 16;
        if (sec == 0) {
          #pragma unroll
          for (int r = 0; r < 4; ++r) {
            const size_t row = rbase + i * 16 + r;
            qb[row * 1024 + col] = f2bf(acc[i][j][r] * QSCALE);
          }
        } else if (sec == 1) {
          const int c2 = col - 1024, hh = c2 >> 6, d = c2 & 63;
          #pragma unroll
          for (int r = 0; r < 4; ++r) {
            const size_t row = rbase + i * 16 + r;
            const int bb = (int)(row >> 11), t = (int)(row & 2047);
            kp[(((size_t)(bb * 16 + hh)) * SEQ + t) * 64 + d] = f2bf(acc[i][j][r]);
          }
        } else {
          const int c2 = col - 2048, hh = c2 >> 6, d = c2 & 63;
          const size_t t0 = rbase + i * 16;
          const int bb = (int)(t0 >> 11);
          u16x4 pk;
          #pragma unroll
          for (int r = 0; r < 4; ++r) pk[r] = f2bf(acc[i][j][r]);
          *(u16x4*)(vt + ((size_t)(bb * 16 + hh) * 64 + d) * SEQ + (t0 & 2047)) = pk;
        }
      }
    }
  } else {
    #pragma unroll
    for (int i = 0; i < 4; ++i) {
      #pragma unroll
      for (int j = 0; j < 4; ++j) {
        const int col = cbase + j * 16;
        const float bval = BIAS ? bias[col] : 0.0f;
        #pragma unroll
        for (int r = 0; r < 4; ++r) {
          const size_t row = rbase + i * 16 + r;
          float v = acc[i][j][r];
          if (BIAS) v += bval;
          if (RELU) v = fmaxf(v, 0.0f);
          if (RES)  v += res[row * N + col];
          if (OBF)  ((unsigned short*)out)[row * N + col] = f2bf(v);
          else      ((float*)out)[row * N + col] = v;
        }
      }
    }
  }
}

// ---------- fused causal attention v4 ----------
// Fixed-max softmax, triangle pairing, XCD swizzle. Q pre-scaled in GEMM epilogue.
__global__ __launch_bounds__(256) void attn4(const unsigned short* __restrict__ qb,
                                             const unsigned short* __restrict__ kp,
                                             const unsigned short* __restrict__ vt,
                                             unsigned short* __restrict__ attnb) {
  const int lin = (blockIdx.z * 16 + blockIdx.y) * 8 + blockIdx.x;  // 512 blocks
  const int xcd = lin & 7, idx = lin >> 3;                          // idx 0..63
  const int bh = xcd * 8 + (idx >> 3);
  const int xb = idx & 7;
  const int b = bh >> 4, h = bh & 15;
  const int tid = threadIdx.x, wave = tid >> 6, lane = tid & 63;
  const int l15 = lane & 15, quad = lane >> 4;
  const size_t tokbase = (size_t)b * SEQ;

  __shared__ __align__(16) unsigned short ks[64 * 64];       // [key][dim], chunk-swizzled
  __shared__ __align__(16) unsigned short vts[64 * 64];      // [dim][key], chunk-swizzled
  __shared__ __align__(16) unsigned short plds[4][32 * 64];  // per-wave P, swizzled

  const unsigned short* kbase = kp + (size_t)bh * SEQ * HDIM;
  const unsigned short* vbase = vt + (size_t)bh * HDIM * SEQ;

  for (int half = 0; half < 2; ++half) {
    const int qblk = (half == 0) ? (15 - xb) : xb;
    const int qw0 = qblk * 128 + wave * 32;

    bf16x8 qf[2][2];
    #pragma unroll
    for (int mf = 0; mf < 2; ++mf)
      #pragma unroll
      for (int kf = 0; kf < 2; ++kf)
        qf[mf][kf] = load8bf(qb + (tokbase + qw0 + mf * 16 + l15) * 1024
                             + h * HDIM + kf * 32 + quad * 8);

    f32x4 o[2][4] = {};
    float lsum[2][4] = {};

    const int ntiles = qblk * 2 + 2;
    for (int kt = 0; kt < ntiles; ++kt) {
      const int k0 = kt * 64;
      __syncthreads();                       // previous tile fully consumed
      #pragma unroll
      for (int i = 0; i < 2; ++i) {          // stage K tile (8KB)
        const int cid = i * 256 + tid;
        const int r = cid >> 3, p = cid & 7, c = p ^ (r & 7);
        gload16(kbase + (size_t)(k0 + r) * HDIM + c * 8, ks + cid * 8);
      }
      #pragma unroll
      for (int i = 0; i < 2; ++i) {          // stage V^T tile (8KB)
        const int cid = i * 256 + tid;
        const int d = cid >> 3, p = cid & 7, c = p ^ (d & 7);
        gload16(vbase + (size_t)d * SEQ + k0 + c * 8, vts + cid * 8);
      }
      __syncthreads();                       // vmcnt drain -> staged data visible
      if (k0 <= qw0 + 31) {
        // ---- QK^T: 16 MFMAs ----
        f32x4 s[2][4] = {};
        #pragma unroll
        for (int kf = 0; kf < 2; ++kf)
          #pragma unroll
          for (int nf = 0; nf < 4; ++nf) {
            const int row = nf * 16 + l15;
            const int p = (kf * 4 + quad) ^ (row & 7);
            const bf16x8 bk = load8bf(ks + row * 64 + p * 8);
            s[0][nf] = mfma16(qf[0][kf], bk, s[0][nf]);
            s[1][nf] = mfma16(qf[1][kf], bk, s[1][nf]);
          }
        // ---- fixed-max softmax: p = exp2(s), mask, accumulate l, store P ----
        #pragma unroll
        for (int mf = 0; mf < 2; ++mf)
          #pragma unroll
          for (int nf = 0; nf < 4; ++nf) {
            const int key = k0 + nf * 16 + l15;
            #pragma unroll
            for (int r = 0; r < 4; ++r) {
              const int lq = mf * 16 + quad * 4 + r;
              float p = __builtin_amdgcn_exp2f(s[mf][nf][r]);
              p = (key > qw0 + lq) ? 0.0f : p;
              const unsigned int pu = __builtin_bit_cast(unsigned int, p);
              lsum[mf][r] += __builtin_bit_cast(float, pu & 0xFFFF0000u);  // match stored P
              const int pc = ((nf * 16 + l15) >> 3) ^ (lq & 7) ^ ((lq >> 3) & 3);
              plds[wave][lq * 64 + pc * 8 + (l15 & 7)] = (unsigned short)(pu >> 16);
            }
          }
        __builtin_amdgcn_s_waitcnt(0);       // wave-local plds writes -> reads
        // ---- PV: 16 MFMAs ----
        #pragma unroll
        for (int kf = 0; kf < 2; ++kf) {
          bf16x8 pa[2];
          #pragma unroll
          for (int mf = 0; mf < 2; ++mf) {
            const int lq = mf * 16 + l15;
            const int p = (kf * 4 + quad) ^ (lq & 7) ^ ((lq >> 3) & 3);
            pa[mf] = load8bf(&plds[wave][lq * 64 + p * 8]);
          }
          #pragma unroll
          for (int df = 0; df < 4; ++df) {
            const int row = df * 16 + l15;
            const int p = (kf * 4 + quad) ^ (row & 7);
            const bf16x8 vb = load8bf(vts + row * 64 + p * 8);
            o[0][df] = mfma16(pa[0], vb, o[0][df]);
            o[1][df] = mfma16(pa[1], vb, o[1][df]);
          }
        }
      }
    }
    // ---- normalize + write (one butterfly per row, once per half) ----
    #pragma unroll
    for (int mf = 0; mf < 2; ++mf)
      #pragma unroll
      for (int r = 0; r < 4; ++r) {
        float l = lsum[mf][r];
        #pragma unroll
        for (int off = 1; off < 16; off <<= 1) l += __shfl_xor(l, off);
        const float rl = 1.0f / l;
        const size_t row = tokbase + qw0 + mf * 16 + quad * 4 + r;
        #pragma unroll
        for (int df = 0; df < 4; ++df)
          attnb[row * D_MODEL + h * HDIM + df * 16 + l15] = f2bf(o[mf][df][r] * rl);
      }
  }
}

// ---------- host ----------
extern "C" void kernel_launch(void* const* d_in, const int* in_sizes, int n_in,
                              void* d_out, int out_size, void* d_ws, size_t ws_size,
                              hipStream_t stream) {
  const float* x    = (const float*)d_in[0];
  const float* wq   = (const float*)d_in[1];
  const float* wk   = (const float*)d_in[2];
  const float* wv   = (const float*)d_in[3];
  const float* wo   = (const float*)d_in[4];
  const float* bo   = (const float*)d_in[5];
  const float* w1   = (const float*)d_in[6];
  const float* b1   = (const float*)d_in[7];
  const float* w2   = (const float*)d_in[8];
  const float* b2   = (const float*)d_in[9];
  const float* g1   = (const float*)d_in[10];
  const float* bl1  = (const float*)d_in[11];
  const float* g2   = (const float*)d_in[12];
  const float* bl2  = (const float*)d_in[13];
  float* out = (float*)d_out;

  char* ws = (char*)d_ws;
  size_t off = 0;
  auto alloc = [&](size_t bytes) { char* p = ws + off; off += (bytes + 255) & ~(size_t)255; return p; };
  unsigned short* wqkv_t = (unsigned short*)alloc((size_t)3072 * 1024 * 2);
  unsigned short* wo_t   = (unsigned short*)alloc((size_t)1024 * 1024 * 2);
  unsigned short* w1_t   = (unsigned short*)alloc((size_t)4096 * 1024 * 2);
  unsigned short* w2_t   = (unsigned short*)alloc((size_t)1024 * 4096 * 2);
  unsigned short* h1     = (unsigned short*)alloc((size_t)NTOK * 1024 * 2);
  unsigned short* kpb    = (unsigned short*)alloc((size_t)NTOK * 1024 * 2);  // K packed
  unsigned short* vtb    = (unsigned short*)alloc((size_t)NTOK * 1024 * 2);  // V^T packed
  unsigned short* attnb  = (unsigned short*)alloc((size_t)NTOK * 1024 * 2);
  unsigned short* h2     = (unsigned short*)alloc((size_t)NTOK * 1024 * 2);
  unsigned short* ffn1   = (unsigned short*)alloc((size_t)NTOK * 4096 * 2);
  // qb aliases attnb: each (b,h,row-slice) of qb is read only by the single attn
  // block that later writes the same attnb slice, and reads precede writes.
  unsigned short* qb = attnb;

  tcast_all<<<12288, 256, 0, stream>>>(wq, wk, wv, wo, w1, w2,
                                       wqkv_t, wo_t, w1_t, w2_t);
  ln_kernel<<<NTOK, 256, 0, stream>>>(x, g1, bl1, h1);
  // fused QKV: writes qb (pre-scaled Q), kp, vt directly
  gemm_bt<false, false, false, true, true><<<dim3(24, 64), 256, 0, stream>>>(
      h1, wqkv_t, nullptr, nullptr, nullptr, qb, kpb, vtb, NTOK, 3072, 1024);
  attn4<<<dim3(SEQ / 256, NHEAD, NBATCH), 256, 0, stream>>>(qb, kpb, vtb, attnb);
  gemm_bt<true, false, true, false, false><<<dim3(8, 64), 256, 0, stream>>>(
      attnb, wo_t, bo, x, out, nullptr, nullptr, nullptr, NTOK, 1024, 1024);
  ln_kernel<<<NTOK, 256, 0, stream>>>(out, g2, bl2, h2);
  gemm_bt<true, true, false, true, false><<<dim3(32, 64), 256, 0, stream>>>(
      h2, w1_t, b1, nullptr, ffn1, nullptr, nullptr, nullptr, NTOK, 4096, 1024);
  gemm_bt<true, false, true, false, false><<<dim3(8, 64), 256, 0, stream>>>(
      ffn1, w2_t, b2, out, out, nullptr, nullptr, nullptr, NTOK, 1024, 4096);
  (void)in_sizes; (void)n_in; (void)out_size; (void)ws_size;
}

// Round 7
// 467.334 us; speedup vs baseline: 2.0287x; 1.0258x over previous
//
#include <hip/hip_runtime.h>
#include <cstdint>

// ---------- types ----------
typedef __bf16 bf16x8 __attribute__((ext_vector_type(8)));
typedef float f32x4 __attribute__((ext_vector_type(4)));
typedef unsigned int u32x4 __attribute__((ext_vector_type(4)));
typedef unsigned int u32x2 __attribute__((ext_vector_type(2)));
typedef unsigned short u16x4 __attribute__((ext_vector_type(4)));

#define D_MODEL 1024
#define SEQ     2048
#define NBATCH  4
#define NHEAD   16
#define HDIM    64
#define NTOK    (NBATCH * SEQ)   // 8192
#define QSCALE  0.18033688011112042f   // 0.125 * log2(e)

__device__ __forceinline__ unsigned short f2bf(float f) {
  unsigned int u = __builtin_bit_cast(unsigned int, f);
  u += 0x7FFFu + ((u >> 16) & 1u);           // round-to-nearest-even
  return (unsigned short)(u >> 16);
}

__device__ __forceinline__ float bf2f(unsigned short s) {
  return __builtin_bit_cast(float, (unsigned int)s << 16);
}

__device__ __forceinline__ bf16x8 load8bf(const unsigned short* p) {
  return __builtin_bit_cast(bf16x8, *(const u32x4*)p);
}

__device__ __forceinline__ f32x4 mfma16(bf16x8 a, bf16x8 b, f32x4 c) {
  return __builtin_amdgcn_mfma_f32_16x16x32_bf16(a, b, c, 0, 0, 0);
}

// async global->LDS, 16B per lane; LDS dest must be waveBase + lane*16
__device__ __forceinline__ void gload16(const unsigned short* g, unsigned short* l) {
  __builtin_amdgcn_global_load_lds((__attribute__((address_space(1))) void*)g,
                                   (__attribute__((address_space(3))) void*)l, 16, 0, 0);
}

// ---------- batched transposing weight cast: out[n][k] = bf16(in[k][n]) ----------
__global__ __launch_bounds__(256) void tcast_all(const float* __restrict__ wq,
                                                 const float* __restrict__ wk,
                                                 const float* __restrict__ wv,
                                                 const float* __restrict__ wo,
                                                 const float* __restrict__ w1,
                                                 const float* __restrict__ w2,
                                                 unsigned short* __restrict__ wqkv_t,
                                                 unsigned short* __restrict__ wo_t,
                                                 unsigned short* __restrict__ w1_t,
                                                 unsigned short* __restrict__ w2_t) {
  const int id = blockIdx.x;
  const float* in; unsigned short* out; int K, N, k0, n0;
  if (id < 4096) {             // wq/wk/wv/wo: 1024x1024 each
    const int seg = id >> 10, r = id & 1023;
    in  = seg == 0 ? wq : seg == 1 ? wk : seg == 2 ? wv : wo;
    out = seg == 3 ? wo_t : wqkv_t + (size_t)seg * 1024 * 1024;
    K = 1024; N = 1024; n0 = (r & 31) * 32; k0 = (r >> 5) * 32;
  } else if (id < 8192) {      // w1: K=1024 -> N=4096
    const int r = id - 4096;
    in = w1; out = w1_t; K = 1024; N = 4096;
    n0 = (r & 127) * 32; k0 = (r >> 7) * 32;
  } else {                     // w2: K=4096 -> N=1024
    const int r = id - 8192;
    in = w2; out = w2_t; K = 4096; N = 1024;
    n0 = (r & 31) * 32; k0 = (r >> 5) * 32;
  }
  __shared__ float tile[32][33];
  const int tx = threadIdx.x & 31, ty = threadIdx.x >> 5;
  #pragma unroll
  for (int j = 0; j < 4; ++j)
    tile[ty + 8 * j][tx] = in[(size_t)(k0 + ty + 8 * j) * N + n0 + tx];
  __syncthreads();
  #pragma unroll
  for (int j = 0; j < 4; ++j)
    out[(size_t)(n0 + ty + 8 * j) * K + k0 + tx] = f2bf(tile[tx][ty + 8 * j]);
}

// ---------- layernorm (D=1024): FPIN=1 fp32 input, else bf16 input ----------
template <int FPIN>
__global__ __launch_bounds__(256) void ln_kernel(const void* __restrict__ xin,
                                                 const float* __restrict__ g,
                                                 const float* __restrict__ bb,
                                                 unsigned short* __restrict__ out) {
  const int row = blockIdx.x, tid = threadIdx.x;
  float4 xv;
  if (FPIN) {
    xv = ((const float4*)((const float*)xin + (size_t)row * D_MODEL))[tid];
  } else {
    const u16x4 bv4 = ((const u16x4*)((const unsigned short*)xin + (size_t)row * D_MODEL))[tid];
    xv.x = bf2f(bv4.x); xv.y = bf2f(bv4.y); xv.z = bf2f(bv4.z); xv.w = bf2f(bv4.w);
  }
  float s  = xv.x + xv.y + xv.z + xv.w;
  float ss = xv.x * xv.x + xv.y * xv.y + xv.z * xv.z + xv.w * xv.w;
  #pragma unroll
  for (int off = 1; off < 64; off <<= 1) { s += __shfl_xor(s, off); ss += __shfl_xor(ss, off); }
  __shared__ float red[8];
  const int wave = tid >> 6, lane = tid & 63;
  if (lane == 0) { red[wave] = s; red[4 + wave] = ss; }
  __syncthreads();
  s  = red[0] + red[1] + red[2] + red[3];
  ss = red[4] + red[5] + red[6] + red[7];
  const float mu   = s * (1.0f / D_MODEL);
  const float var  = ss * (1.0f / D_MODEL) - mu * mu;
  const float rstd = rsqrtf(var + 1e-5f);
  const float4 gv = ((const float4*)g)[tid];
  const float4 bv = ((const float4*)bb)[tid];
  u16x4 o;
  o.x = f2bf((xv.x - mu) * rstd * gv.x + bv.x);
  o.y = f2bf((xv.y - mu) * rstd * gv.y + bv.y);
  o.z = f2bf((xv.z - mu) * rstd * gv.z + bv.z);
  o.w = f2bf((xv.w - mu) * rstd * gv.w + bv.w);
  *(u16x4*)(out + (size_t)row * D_MODEL + tid * 4) = o;
}

// ---------- GEMM: C[M,N] = A[M,K](bf16) * Bt[N,K](bf16)^T ----------
// 128x128 tile, BK=64, chunk-XOR swizzled LDS (0 conflicts), XCD-banded order.
// RES: 0=none, 1=fp32 residual, 2=bf16 residual. QKV: scatter epilogue.
template <bool BIAS, bool RELU, int RES, bool OBF, bool QKV>
__global__ __launch_bounds__(256) void gemm_bt(const unsigned short* __restrict__ A,
                                               const unsigned short* __restrict__ Bt,
                                               const float* __restrict__ bias,
                                               const void* __restrict__ res,
                                               void* __restrict__ out,
                                               unsigned short* __restrict__ qb,
                                               unsigned short* __restrict__ kp,
                                               unsigned short* __restrict__ vt,
                                               int M, int N, int K) {
  __shared__ __align__(16) unsigned short As[128 * 64];
  __shared__ __align__(16) unsigned short Bs[128 * 64];
  const int tid  = threadIdx.x;
  const int lin = blockIdx.y * gridDim.x + blockIdx.x;   // gridDim.y == 64 always
  const int xcd = lin & 7, idx = lin >> 3;
  const int by = xcd * 8 + (idx & 7);
  const int bx = idx >> 3;
  const int row0 = by * 128, col0 = bx * 128;
  const int wave = tid >> 6, lane = tid & 63;
  const int wm = wave >> 1, wn = wave & 1;
  const int l15 = lane & 15, quad = lane >> 4;
  f32x4 acc[4][4] = {};

  const int tr = tid >> 3;                        // base row 0..31
  const int tc = (tid & 7) ^ (tr & 7);            // swizzled source chunk
  const unsigned short* gA = A  + (size_t)(row0 + tr) * K + tc * 8;
  const unsigned short* gB = Bt + (size_t)(col0 + tr) * K + tc * 8;

  const int rowA = (wm * 64 + l15) * 64;
  const int rowB = (wn * 64 + l15) * 64;
  const int swz0 = (quad ^ (l15 & 7)) * 8;
  const int swz1 = ((4 + quad) ^ (l15 & 7)) * 8;

  for (int k0 = 0; k0 < K; k0 += 64) {
    #pragma unroll
    for (int i = 0; i < 4; ++i) {
      gload16(gA + (size_t)(i * 32) * K + k0, As + (i * 256 + tid) * 8);
      gload16(gB + (size_t)(i * 32) * K + k0, Bs + (i * 256 + tid) * 8);
    }
    __syncthreads();
    #pragma unroll
    for (int kf = 0; kf < 2; ++kf) {
      const int swz = kf ? swz1 : swz0;
      bf16x8 af[4], bfr[4];
      #pragma unroll
      for (int t = 0; t < 4; ++t) {
        af[t]  = load8bf(As + rowA + t * 1024 + swz);
        bfr[t] = load8bf(Bs + rowB + t * 1024 + swz);
      }
      #pragma unroll
      for (int i = 0; i < 4; ++i)
        #pragma unroll
        for (int j = 0; j < 4; ++j)
          acc[i][j] = mfma16(af[i], bfr[j], acc[i][j]);
    }
    __syncthreads();
  }

  const size_t rbase = (size_t)row0 + wm * 64 + quad * 4;
  const int cbase = col0 + wn * 64 + l15;
  if (QKV) {
    const int sec = col0 >> 10;           // block-uniform: 0=Q, 1=K, 2=V
    #pragma unroll
    for (int i = 0; i < 4; ++i) {
      #pragma unroll
      for (int j = 0; j < 4; ++j) {
        const int col = cbase + j * 16;
        if (sec == 0) {
          #pragma unroll
          for (int r = 0; r < 4; ++r) {
            const size_t row = rbase + i * 16 + r;
            qb[row * 1024 + col] = f2bf(acc[i][j][r] * QSCALE);
          }
        } else if (sec == 1) {
          const int c2 = col - 1024, hh = c2 >> 6, d = c2 & 63;
          #pragma unroll
          for (int r = 0; r < 4; ++r) {
            const size_t row = rbase + i * 16 + r;
            const int bb = (int)(row >> 11), t = (int)(row & 2047);
            kp[(((size_t)(bb * 16 + hh)) * SEQ + t) * 64 + d] = f2bf(acc[i][j][r]);
          }
        } else {
          const int c2 = col - 2048, hh = c2 >> 6, d = c2 & 63;
          const size_t t0 = rbase + i * 16;
          const int bb = (int)(t0 >> 11);
          u16x4 pk;
          #pragma unroll
          for (int r = 0; r < 4; ++r) pk[r] = f2bf(acc[i][j][r]);
          *(u16x4*)(vt + ((size_t)(bb * 16 + hh) * 64 + d) * SEQ + (t0 & 2047)) = pk;
        }
      }
    }
  } else {
    #pragma unroll
    for (int i = 0; i < 4; ++i) {
      #pragma unroll
      for (int j = 0; j < 4; ++j) {
        const int col = cbase + j * 16;
        const float bval = BIAS ? bias[col] : 0.0f;
        #pragma unroll
        for (int r = 0; r < 4; ++r) {
          const size_t row = rbase + i * 16 + r;
          float v = acc[i][j][r];
          if (BIAS) v += bval;
          if (RELU) v = fmaxf(v, 0.0f);
          if (RES == 1) v += ((const float*)res)[row * N + col];
          if (RES == 2) v += bf2f(((const unsigned short*)res)[row * N + col]);
          if (OBF)  ((unsigned short*)out)[row * N + col] = f2bf(v);
          else      ((float*)out)[row * N + col] = v;
        }
      }
    }
  }
}

// ---------- fused causal attention v5 ----------
// QK^T with SWAPPED operands (A=K, B=Q): S^T has key on rows, query on lanes.
// -> lsum is pure in-lane per query; P stores are packed ds_write_b64 (4 keys of
// one query row). Fixed-max softmax, triangle pairing, XCD swizzle.
__global__ __launch_bounds__(256) void attn5(const unsigned short* __restrict__ qb,
                                             const unsigned short* __restrict__ kp,
                                             const unsigned short* __restrict__ vt,
                                             unsigned short* __restrict__ attnb) {
  const int lin = (blockIdx.z * 16 + blockIdx.y) * 8 + blockIdx.x;  // 512 blocks
  const int xcd = lin & 7, idx = lin >> 3;
  const int bh = xcd * 8 + (idx >> 3);
  const int xb = idx & 7;
  const int b = bh >> 4, h = bh & 15;
  const int tid = threadIdx.x, wave = tid >> 6, lane = tid & 63;
  const int l15 = lane & 15, quad = lane >> 4;
  const size_t tokbase = (size_t)b * SEQ;

  __shared__ __align__(16) unsigned short ks[64 * 64];       // [key][dim], chunk-swizzled
  __shared__ __align__(16) unsigned short vts[64 * 64];      // [dim][key], chunk-swizzled
  __shared__ __align__(16) unsigned short plds[4][32 * 64];  // per-wave P[q][key], swizzled

  const unsigned short* kbase = kp + (size_t)bh * SEQ * HDIM;
  const unsigned short* vbase = vt + (size_t)bh * HDIM * SEQ;

  for (int half = 0; half < 2; ++half) {
    const int qblk = (half == 0) ? (15 - xb) : xb;
    const int qw0 = qblk * 128 + wave * 32;

    bf16x8 qf[2][2];   // [qf][kf]: rows qw0+qf*16+l15, dims kf*32+quad*8..+8
    #pragma unroll
    for (int qfi = 0; qfi < 2; ++qfi)
      #pragma unroll
      for (int kf = 0; kf < 2; ++kf)
        qf[qfi][kf] = load8bf(qb + (tokbase + qw0 + qfi * 16 + l15) * 1024
                              + h * HDIM + kf * 32 + quad * 8);

    f32x4 o[2][4] = {};
    float lsum[2] = {0.0f, 0.0f};

    const int ntiles = qblk * 2 + 2;
    for (int kt = 0; kt < ntiles; ++kt) {
      const int k0 = kt * 64;
      __syncthreads();                       // previous tile fully consumed
      #pragma unroll
      for (int i = 0; i < 2; ++i) {          // stage K tile (8KB)
        const int cid = i * 256 + tid;
        const int r = cid >> 3, p = cid & 7, c = p ^ (r & 7);
        gload16(kbase + (size_t)(k0 + r) * HDIM + c * 8, ks + cid * 8);
      }
      #pragma unroll
      for (int i = 0; i < 2; ++i) {          // stage V^T tile (8KB)
        const int cid = i * 256 + tid;
        const int d = cid >> 3, p = cid & 7, c = p ^ (d & 7);
        gload16(vbase + (size_t)d * SEQ + k0 + c * 8, vts + cid * 8);
      }
      __syncthreads();                       // vmcnt drain -> staged data visible
      if (k0 <= qw0 + 31) {
        // ---- QK^T (swapped): s[keyf][qfi], value(key=k0+keyf*16+quad*4+r,
        //                                          q=qw0+qfi*16+l15) ----
        f32x4 s[4][2] = {};
        #pragma unroll
        for (int kf = 0; kf < 2; ++kf)
          #pragma unroll
          for (int keyf = 0; keyf < 4; ++keyf) {
            const int row = keyf * 16 + l15;
            const int p = (kf * 4 + quad) ^ (row & 7);
            const bf16x8 kfr = load8bf(ks + row * 64 + p * 8);
            s[keyf][0] = mfma16(kfr, qf[0][kf], s[keyf][0]);
            s[keyf][1] = mfma16(kfr, qf[1][kf], s[keyf][1]);
          }
        // ---- fixed-max softmax + packed P store ----
        #pragma unroll
        for (int qfi = 0; qfi < 2; ++qfi) {
          const int q = qw0 + qfi * 16 + l15;
          const int qloc = qfi * 16 + l15;
          #pragma unroll
          for (int keyf = 0; keyf < 4; ++keyf) {
            unsigned int pw[4];
            #pragma unroll
            for (int r = 0; r < 4; ++r) {
              const int key = k0 + keyf * 16 + quad * 4 + r;
              float p = __builtin_amdgcn_exp2f(s[keyf][qfi][r]);
              p = (key > q) ? 0.0f : p;
              pw[r] = __builtin_bit_cast(unsigned int, p);
              lsum[qfi] += __builtin_bit_cast(float, pw[r] & 0xFFFF0000u);
            }
            u32x2 packed;
            packed.x = (pw[0] >> 16) | (pw[1] & 0xFFFF0000u);
            packed.y = (pw[2] >> 16) | (pw[3] & 0xFFFF0000u);
            const int slot = (keyf * 4 + quad) ^ ((l15 & 7) << 1);
            *(u32x2*)(&plds[wave][qloc * 64 + slot * 4]) = packed;
          }
        }
        __builtin_amdgcn_s_waitcnt(0);       // wave-local plds writes -> reads
        // ---- PV: A=P (m=q,k=key), B=V^T (n=d,k=key) ----
        #pragma unroll
        for (int kf = 0; kf < 2; ++kf) {
          bf16x8 pa[2];
          #pragma unroll
          for (int mf = 0; mf < 2; ++mf) {
            const int lq = mf * 16 + l15;
            const int c = (kf * 4 + quad) ^ (l15 & 7);
            pa[mf] = load8bf(&plds[wave][lq * 64 + c * 8]);
          }
          #pragma unroll
          for (int df = 0; df < 4; ++df) {
            const int row = df * 16 + l15;
            const int p = (kf * 4 + quad) ^ (row & 7);
            const bf16x8 vb = load8bf(vts + row * 64 + p * 8);
            o[0][df] = mfma16(pa[0], vb, o[0][df]);
            o[1][df] = mfma16(pa[1], vb, o[1][df]);
          }
        }
      }
    }
    // ---- normalize + write: lsum[qfi] is per-lane (q=qw0+qfi*16+l15),
    //      partial over quads -> 2 butterflies, then bpermute to C-layout rows ----
    #pragma unroll
    for (int mf = 0; mf < 2; ++mf) {
      float l = lsum[mf];
      l += __shfl_xor(l, 16);
      l += __shfl_xor(l, 32);
      const float rl = 1.0f / l;
      #pragma unroll
      for (int r = 0; r < 4; ++r) {
        const float rv = __shfl(rl, quad * 4 + r);   // lane holding q=..+quad*4+r
        const size_t row = tokbase + qw0 + mf * 16 + quad * 4 + r;
        #pragma unroll
        for (int df = 0; df < 4; ++df)
          attnb[row * D_MODEL + h * HDIM + df * 16 + l15] = f2bf(o[mf][df][r] * rv);
      }
    }
  }
}

// ---------- host ----------
extern "C" void kernel_launch(void* const* d_in, const int* in_sizes, int n_in,
                              void* d_out, int out_size, void* d_ws, size_t ws_size,
                              hipStream_t stream) {
  const float* x    = (const float*)d_in[0];
  const float* wq   = (const float*)d_in[1];
  const float* wk   = (const float*)d_in[2];
  const float* wv   = (const float*)d_in[3];
  const float* wo   = (const float*)d_in[4];
  const float* bo   = (const float*)d_in[5];
  const float* w1   = (const float*)d_in[6];
  const float* b1   = (const float*)d_in[7];
  const float* w2   = (const float*)d_in[8];
  const float* b2   = (const float*)d_in[9];
  const float* g1   = (const float*)d_in[10];
  const float* bl1  = (const float*)d_in[11];
  const float* g2   = (const float*)d_in[12];
  const float* bl2  = (const float*)d_in[13];
  float* out = (float*)d_out;

  char* ws = (char*)d_ws;
  size_t off = 0;
  auto alloc = [&](size_t bytes) { char* p = ws + off; off += (bytes + 255) & ~(size_t)255; return p; };
  unsigned short* wqkv_t = (unsigned short*)alloc((size_t)3072 * 1024 * 2);
  unsigned short* wo_t   = (unsigned short*)alloc((size_t)1024 * 1024 * 2);
  unsigned short* w1_t   = (unsigned short*)alloc((size_t)4096 * 1024 * 2);
  unsigned short* w2_t   = (unsigned short*)alloc((size_t)1024 * 4096 * 2);
  unsigned short* h1     = (unsigned short*)alloc((size_t)NTOK * 1024 * 2);
  unsigned short* kpb    = (unsigned short*)alloc((size_t)NTOK * 1024 * 2);  // K packed
  unsigned short* vtb    = (unsigned short*)alloc((size_t)NTOK * 1024 * 2);  // V^T packed
  unsigned short* attnb  = (unsigned short*)alloc((size_t)NTOK * 1024 * 2);
  unsigned short* h2     = (unsigned short*)alloc((size_t)NTOK * 1024 * 2);
  unsigned short* ffn1   = (unsigned short*)alloc((size_t)NTOK * 4096 * 2);
  // qb aliases attnb (reads precede writes within each attn block, disjoint
  // (row,h)-slices across blocks). x1b aliases h1 (dead after QKV GEMM).
  unsigned short* qb  = attnb;
  unsigned short* x1b = h1;

  tcast_all<<<12288, 256, 0, stream>>>(wq, wk, wv, wo, w1, w2,
                                       wqkv_t, wo_t, w1_t, w2_t);
  ln_kernel<1><<<NTOK, 256, 0, stream>>>(x, g1, bl1, h1);
  // fused QKV: writes qb (pre-scaled Q), kp, vt directly
  gemm_bt<false, false, 0, true, true><<<dim3(24, 64), 256, 0, stream>>>(
      h1, wqkv_t, nullptr, nullptr, nullptr, qb, kpb, vtb, NTOK, 3072, 1024);
  attn5<<<dim3(SEQ / 256, NHEAD, NBATCH), 256, 0, stream>>>(qb, kpb, vtb, attnb);
  // x1 = x + attn @ wo + bo  -> bf16 x1b
  gemm_bt<true, false, 1, true, false><<<dim3(8, 64), 256, 0, stream>>>(
      attnb, wo_t, bo, x, x1b, nullptr, nullptr, nullptr, NTOK, 1024, 1024);
  ln_kernel<0><<<NTOK, 256, 0, stream>>>(x1b, g2, bl2, h2);
  gemm_bt<true, true, 0, true, false><<<dim3(32, 64), 256, 0, stream>>>(
      h2, w1_t, b1, nullptr, ffn1, nullptr, nullptr, nullptr, NTOK, 4096, 1024);
  // out = x1b + ffn1 @ w2 + b2 (fp32 out, bf16 residual)
  gemm_bt<true, false, 2, false, false><<<dim3(8, 64), 256, 0, stream>>>(
      ffn1, w2_t, b2, x1b, out, nullptr, nullptr, nullptr, NTOK, 1024, 4096);
  (void)in_sizes; (void)n_in; (void)out_size; (void)ws_size;
}